// Round 1
// baseline (1441.432 us; speedup 1.0000x reference)
//
#include <hip/hip_runtime.h>
#include <hip/hip_bf16.h>

// Sizes (fixed by the problem)
#define BATCH 128
#define CCOND 16          // conditioning channels
#define CX    8           // flow channels
#define CIN0  24          // CCOND + CX
#define HID   32
#define LLEN  8192
#define NSTEP 2
#define PDIM  23          // 3K-1, K=8
#define POUT  184         // PDIM * CX

#define TILE 256
#define NT   256
#define HALO 4
#define WIN  (TILE + 2*HALO)   // 264
#define STR  33                // padded channel stride in LDS ([pos][33])
#define PSTR 48                // per-(b,c) param record stride in ws

// ---------------------------------------------------------------- init / util
__global__ void init_kernel(const float* __restrict__ noise,
                            float* __restrict__ x,
                            float* __restrict__ logdet) {
    int i = blockIdx.x * 256 + threadIdx.x;
    x[i] = noise[i];
    if (i < BATCH) logdet[i] = 0.f;
}

__global__ void zero_kernel(float* __restrict__ p, int n) {
    int i = blockIdx.x * 256 + threadIdx.x;
    if (i < n) p[i] = 0.f;
}

// Repack conv weights to [t][ci][k][co] (contiguous in co) so the conv kernel's
// weight reads are wave-uniform contiguous -> batched s_load_dwordx16.
__global__ void repack_kernel(const float* __restrict__ w0,   // [2][32][24][3]
                              const float* __restrict__ wh,   // [2][3][32][32][3]
                              float* __restrict__ wt0,        // [2][24][3][32]
                              float* __restrict__ wth) {      // [2][3][32][3][32]
    int i = blockIdx.x * 256 + threadIdx.x;
    if (i < 2 * CIN0 * 3 * HID) {                 // 4608
        int t = i / (CIN0 * 3 * HID), r = i % (CIN0 * 3 * HID);
        int ci = r / (3 * HID), r2 = r % (3 * HID);
        int k = r2 / HID, co = r2 % HID;
        wt0[i] = w0[((t * HID + co) * CIN0 + ci) * 3 + k];
    }
    if (i < 2 * 3 * HID * 3 * HID) {              // 18432
        int t = i / (3 * HID * 3 * HID), r = i % (3 * HID * 3 * HID);
        int j = r / (HID * 3 * HID), r2 = r % (HID * 3 * HID);
        int ci = r2 / (3 * HID), r3 = r2 % (3 * HID);
        int k = r3 / HID, co = r3 % HID;
        wth[i] = wh[(((t * 3 + j) * HID + co) * HID + ci) * 3 + k];
    }
}

// ---------------------------------------------------------------- fused convs
// One conv layer inside the fused kernel. Input buf covers positions
// [gfirst-1, gfirst-1+Wout+1]; output index o corresponds to global pos
// gfirst+o. Positions outside [0,L) are zero (matches SAME zero padding at
// every layer). Weights: [ci][k][co] contiguous (96 floats per ci).
template<int CI>
__device__ __forceinline__ void conv_layer(const float* __restrict__ w,
                                           const float* __restrict__ bias,
                                           const float* __restrict__ inbuf,
                                           float* __restrict__ outbuf,
                                           int Wout, int gfirst) {
    for (int o = threadIdx.x; o < Wout; o += NT) {
        int g = gfirst + o;
        if ((unsigned)g < (unsigned)LLEN) {
            float acc[HID];
            #pragma unroll
            for (int co = 0; co < HID; co++) acc[co] = bias[co];
            #pragma unroll 4
            for (int ci = 0; ci < CI; ci++) {
                float x0 = inbuf[(o    ) * STR + ci];
                float x1 = inbuf[(o + 1) * STR + ci];
                float x2 = inbuf[(o + 2) * STR + ci];
                const float* wp = w + ci * (3 * HID);
                #pragma unroll
                for (int co = 0; co < HID; co++) {
                    acc[co] = fmaf(wp[co], x0,
                              fmaf(wp[HID + co], x1,
                              fmaf(wp[2 * HID + co], x2, acc[co])));
                }
            }
            #pragma unroll
            for (int co = 0; co < HID; co++)
                outbuf[o * STR + co] = fmaxf(acc[co], 0.f);
        } else {
            #pragma unroll
            for (int co = 0; co < HID; co++) outbuf[o * STR + co] = 0.f;
        }
    }
    __syncthreads();
}

// Fused: stage (c,x) tile -> conv0 -> h1 -> h2 -> h3 -> partial L-mean of h3.
__global__ __launch_bounds__(256) void conv_kernel(
        const float* __restrict__ cin,   // [B][16][L]
        const float* __restrict__ xin,   // [B][8][L]
        const float* __restrict__ wt0,   // [24][3][32] for this t
        const float* __restrict__ b0,    // [32]
        const float* __restrict__ wth,   // [3][32][3][32] for this t
        const float* __restrict__ bh,    // [3][32]
        float* __restrict__ hbar) {      // [B][32] (sums, atomically accumulated)
    __shared__ float bufA[WIN * STR];
    __shared__ float bufB[WIN * STR];
    __shared__ float psum[NT];

    const int b = blockIdx.y;
    const int gbase = blockIdx.x * TILE;
    const int tid = threadIdx.x;

    // stage input: channels 0..15 = c, 16..23 = x, zero outside [0,L)
    for (int pos = tid; pos < WIN; pos += NT) {
        int g = gbase - HALO + pos;
        bool ok = (unsigned)g < (unsigned)LLEN;
        float* dst = &bufA[pos * STR];
        #pragma unroll
        for (int ci = 0; ci < CCOND; ci++)
            dst[ci] = ok ? cin[((size_t)b * CCOND + ci) * LLEN + g] : 0.f;
        #pragma unroll
        for (int ci = 0; ci < CX; ci++)
            dst[CCOND + ci] = ok ? xin[((size_t)b * CX + ci) * LLEN + g] : 0.f;
    }
    __syncthreads();

    conv_layer<CIN0>(wt0,                 b0,      bufA, bufB, WIN - 2, gbase - HALO + 1);
    conv_layer<HID >(wth,                 bh,      bufB, bufA, WIN - 4, gbase - HALO + 2);
    conv_layer<HID >(wth + 1 * HID * 3 * HID, bh + HID,     bufA, bufB, WIN - 6, gbase - HALO + 3);
    conv_layer<HID >(wth + 2 * HID * 3 * HID, bh + 2 * HID, bufB, bufA, TILE,    gbase);

    // partial mean over this tile: bufA[0..255][ch]
    int ch = tid & 31, seg = tid >> 5;
    float s = 0.f;
    #pragma unroll
    for (int i = 0; i < 32; i++) s += bufA[(seg * 32 + i) * STR + ch];
    psum[tid] = s;
    __syncthreads();
    if (tid < HID) {
        float tot = 0.f;
        #pragma unroll
        for (int sg = 0; sg < 8; sg++) tot += psum[sg * 32 + tid];
        atomicAdd(&hbar[b * HID + tid], tot);
    }
}

// ---------------------------------------------------------------- spline prep
__device__ __forceinline__ float softplusf(float v) {
    return fmaxf(v, 0.f) + log1pf(expf(-fabsf(v)));
}

// One thread per (b,c): p = w_out * mean(h) + b_out, then knot arrays.
// Record layout (stride PSTR): cw[0..8], ch[9..17], w[18..25], h[26..33], d[34..42]
__global__ void params_kernel(const float* __restrict__ hbar,   // [B][32] sums
                              const float* __restrict__ w_out,  // [184][32] for this t
                              const float* __restrict__ b_out,  // [184]
                              float* __restrict__ params) {
    int tg = blockIdx.x * 256 + threadIdx.x;
    if (tg >= BATCH * CX) return;
    int b = tg >> 3, c = tg & 7;
    const float invL = 1.0f / (float)LLEN;

    float hb[HID];
    #pragma unroll
    for (int h = 0; h < HID; h++) hb[h] = hbar[b * HID + h] * invL;

    float p[PDIM];
    #pragma unroll
    for (int j = 0; j < PDIM; j++) {
        int cp = c * PDIM + j;
        float acc = b_out[cp];
        #pragma unroll
        for (int h = 0; h < HID; h++) acc = fmaf(w_out[cp * HID + h], hb[h], acc);
        p[j] = acc;
    }

    float* out = params + (size_t)tg * PSTR;

    // widths -> knot x positions
    {
        float mx = p[0];
        #pragma unroll
        for (int k = 1; k < 8; k++) mx = fmaxf(mx, p[k]);
        float e[8], se = 0.f;
        #pragma unroll
        for (int k = 0; k < 8; k++) { e[k] = expf(p[k] - mx); se += e[k]; }
        float inv = 1.f / se, cum = 0.f;
        float cw[9]; cw[0] = -3.f;
        #pragma unroll
        for (int k = 0; k < 8; k++) {
            float wk = 1e-3f + (1.f - 8e-3f) * (e[k] * inv);
            cum += wk;
            cw[k + 1] = 6.f * cum - 3.f;
        }
        #pragma unroll
        for (int k = 0; k < 9; k++) out[k] = cw[k];
        #pragma unroll
        for (int k = 0; k < 8; k++) out[18 + k] = cw[k + 1] - cw[k];
    }
    // heights -> knot y positions
    {
        float mx = p[8];
        #pragma unroll
        for (int k = 1; k < 8; k++) mx = fmaxf(mx, p[8 + k]);
        float e[8], se = 0.f;
        #pragma unroll
        for (int k = 0; k < 8; k++) { e[k] = expf(p[8 + k] - mx); se += e[k]; }
        float inv = 1.f / se, cum = 0.f;
        float ch[9]; ch[0] = -3.f;
        #pragma unroll
        for (int k = 0; k < 8; k++) {
            float hk = 1e-3f + (1.f - 8e-3f) * (e[k] * inv);
            cum += hk;
            ch[k + 1] = 6.f * cum - 3.f;
        }
        #pragma unroll
        for (int k = 0; k < 9; k++) out[9 + k] = ch[k];
        #pragma unroll
        for (int k = 0; k < 8; k++) out[26 + k] = ch[k + 1] - ch[k];
    }
    // derivatives (boundary = 1)
    out[34] = 1.f;
    #pragma unroll
    for (int k = 0; k < 7; k++) out[35 + k] = 1e-3f + softplusf(p[16 + k]);
    out[42] = 1.f;
}

// ---------------------------------------------------------------- RQS inverse
__global__ __launch_bounds__(256) void rqs_kernel(const float* __restrict__ params,
                                                  float* __restrict__ x,
                                                  float* __restrict__ logdet) {
    __shared__ float pr[43];
    __shared__ float red[4];
    const int bc = blockIdx.y;
    const int tid = threadIdx.x;
    if (tid < 43) pr[tid] = params[(size_t)bc * PSTR + tid];
    __syncthreads();

    const float* cw = pr;
    const float* ch = pr + 9;
    const float* wd = pr + 18;
    const float* hg = pr + 26;
    const float* dv = pr + 34;

    int pos = blockIdx.x * 256 + tid;
    size_t xi = (size_t)bc * LLEN + pos;
    float y = x[xi];
    bool inside = fabsf(y) <= 3.0f;
    float yc = fminf(fmaxf(y, -3.f), 3.f);

    int idx = 0;
    #pragma unroll
    for (int k = 1; k < 9; k++) idx += (yc >= ch[k]) ? 1 : 0;
    idx = idx > 7 ? 7 : idx;

    float icw = cw[idx], iw = wd[idx], ich = ch[idx], ih = hg[idx];
    float dk = dv[idx], dk1 = dv[idx + 1];

    float s  = ih / iw;
    float dy = yc - ich;
    float t1 = dk + dk1 - 2.f * s;
    float a  = ih * (s - dk) + dy * t1;
    float bq = ih * dk - dy * t1;
    float cq = -s * dy;
    float disc = fmaxf(bq * bq - 4.f * a * cq, 0.f);
    float root = (2.f * cq) / (-bq - sqrtf(disc));
    float om = 1.f - root;
    float outv  = fmaf(root, iw, icw);
    float denom = fmaf(t1 * root, om, s);
    float dnum  = s * s * (dk1 * root * root + 2.f * s * root * om + dk * om * om);
    float ld = 2.f * logf(denom) - logf(dnum);   // = -(log dnum - 2 log denom)

    x[xi] = inside ? outv : y;
    float ldv = inside ? ld : 0.f;

    #pragma unroll
    for (int off = 32; off > 0; off >>= 1) ldv += __shfl_xor(ldv, off, 64);
    if ((tid & 63) == 0) red[tid >> 6] = ldv;
    __syncthreads();
    if (tid == 0) {
        float sb = red[0] + red[1] + red[2] + red[3];
        atomicAdd(&logdet[bc >> 3], sb * (1.0f / (float)LLEN));
    }
}

// ---------------------------------------------------------------- launch
extern "C" void kernel_launch(void* const* d_in, const int* in_sizes, int n_in,
                              void* d_out, int out_size, void* d_ws, size_t ws_size,
                              hipStream_t stream) {
    const float* cin   = (const float*)d_in[1];
    const float* noise = (const float*)d_in[2];
    const float* w0    = (const float*)d_in[3];
    const float* b0    = (const float*)d_in[4];
    const float* wh    = (const float*)d_in[5];
    const float* bh    = (const float*)d_in[6];
    const float* w_out = (const float*)d_in[7];
    const float* b_out = (const float*)d_in[8];

    float* xout   = (float*)d_out;                       // [128*8*8192]
    float* logdet = xout + (size_t)BATCH * CX * LLEN;    // [128]

    float* ws     = (float*)d_ws;
    float* hbar   = ws;                                  // 4096 floats
    float* params = ws + 4096;                           // 1024*48 floats
    float* wt0    = ws + 4096 + 1024 * PSTR;             // 4608
    float* wth    = wt0 + 2 * CIN0 * 3 * HID;            // 18432

    const int nx = BATCH * CX * LLEN;                    // 8388608
    init_kernel<<<nx / 256, 256, 0, stream>>>(noise, xout, logdet);
    repack_kernel<<<(2 * 3 * HID * 3 * HID + 255) / 256, 256, 0, stream>>>(w0, wh, wt0, wth);

    for (int t = 0; t < NSTEP; t++) {
        zero_kernel<<<(BATCH * HID + 255) / 256, 256, 0, stream>>>(hbar, BATCH * HID);
        conv_kernel<<<dim3(LLEN / TILE, BATCH), 256, 0, stream>>>(
            cin, xout,
            wt0 + t * CIN0 * 3 * HID, b0 + t * HID,
            wth + t * 3 * HID * 3 * HID, bh + t * 3 * HID,
            hbar);
        params_kernel<<<(BATCH * CX + 255) / 256, 256, 0, stream>>>(
            hbar, w_out + t * POUT * HID, b_out + t * POUT, params);
        rqs_kernel<<<dim3(LLEN / TILE, BATCH * CX), 256, 0, stream>>>(params, xout, logdet);
    }
}

// Round 2
// 715.735 us; speedup vs baseline: 2.0139x; 2.0139x over previous
//
#include <hip/hip_runtime.h>
#include <hip/hip_bf16.h>

// Sizes (fixed by the problem)
#define BATCH 128
#define CCOND 16          // conditioning channels
#define CX    8           // flow channels
#define CIN0  24          // CCOND + CX
#define HID   32
#define LLEN  8192
#define NSTEP 2
#define PDIM  23          // 3K-1, K=8
#define POUT  184         // PDIM * CX
#define PSTR  48          // per-(b,c) param record stride in ws

// conv tiling
#define TILE  256         // valid output positions per block
#define ROWS  276         // staged rows: global g in [gbase-5, gbase+271)
#define RSTR  40          // ushort stride per row (80 B -> all 32 banks covered)
#define NT    256

typedef __bf16 bf16x8 __attribute__((ext_vector_type(8)));
typedef float  f32x4  __attribute__((ext_vector_type(4)));

__device__ __forceinline__ unsigned short f2bf(float f) {
    unsigned u = __float_as_uint(f);
    return (unsigned short)((u + 0x7FFFu + ((u >> 16) & 1u)) >> 16);
}

// ---------------------------------------------------------------- init / util
__global__ void init_kernel(const float* __restrict__ noise,
                            float* __restrict__ x,
                            float* __restrict__ logdet) {
    int i = blockIdx.x * 256 + threadIdx.x;
    x[i] = noise[i];
    if (i < BATCH) logdet[i] = 0.f;
}

__global__ void zero_kernel(float* __restrict__ p, int n) {
    int i = blockIdx.x * 256 + threadIdx.x;
    if (i < n) p[i] = 0.f;
}

// Pack conv weights into exact per-lane MFMA A-fragment order (bf16).
// wf[t][layer][s][mt][lane][j]; element = W[co = mt*16+(lane&15)]
//                                          [ci = (lane>>4)*8+j][koff = s]
// K-order is k = koff*32 + ci (layer0: ci>=24 zero-padded).
__global__ void repack_frag_kernel(const float* __restrict__ w0,   // [2][32][24][3]
                                   const float* __restrict__ wh,   // [2][3][32][32][3]
                                   unsigned short* __restrict__ wf) {
    int i = blockIdx.x * 256 + threadIdx.x;     // 24576 total
    int j = i & 7, lane = (i >> 3) & 63, q = i >> 9;
    int mt = q & 1; q >>= 1;
    int s = q % 3;  q /= 3;
    int l = q & 3, t = q >> 2;
    int m = mt * 16 + (lane & 15);
    int ci = (lane >> 4) * 8 + j;
    float v;
    if (l == 0)
        v = (ci < CIN0) ? w0[((t * HID + m) * CIN0 + ci) * 3 + s] : 0.f;
    else
        v = wh[(((t * 3 + (l - 1)) * HID + m) * HID + ci) * 3 + s];
    wf[i] = f2bf(v);
}

// ---------------------------------------------------------------- fused convs
// 4 conv layers fully fused via mfma_f32_16x16x32_bf16.
// Activations live in LDS as bf16 [row][ch] (RSTR=40). B-fragment for lane l =
// 8 contiguous channels at one position -> one ds_read_b128. Layer outputs
// (4 consecutive co per lane) -> one ds_write_b64. Layer 3 skips LDS: its
// accumulators feed the L-mean directly (shfl reduce + atomicAdd).
__global__ __launch_bounds__(256) void conv_kernel(
        const float* __restrict__ cin,   // [B][16][L]
        const float* __restrict__ xin,   // [B][8][L]
        const unsigned short* __restrict__ wf,  // this t: [4][3][2][64][8]
        const float* __restrict__ b0p,   // [32]   (this t)
        const float* __restrict__ bhp,   // [3][32](this t)
        float* __restrict__ hbar) {      // [B][32] sums (atomic)
    __shared__ __align__(16) unsigned short bufA[ROWS * RSTR];
    __shared__ __align__(16) unsigned short bufB[ROWS * RSTR];

    const int b = blockIdx.y;
    const int gbase = blockIdx.x * TILE;
    const int tid = threadIdx.x;
    const int lane = tid & 63, wv = tid >> 6;
    const int prow = lane & 15;          // position within N-tile (D col)
    const int grp  = lane >> 4;          // 0..3
    const int ci0  = grp * 8;            // B-frag channel chunk
    const int co0  = grp * 4;            // D row base within M-tile

    // stage 24 input channels as bf16; channels 24..31 zeroed (K padding)
    for (int e = tid; e < CIN0 * ROWS; e += NT) {
        int ci = e / ROWS, pos = e - ci * ROWS;
        int g = gbase - 5 + pos;
        float v = 0.f;
        if ((unsigned)g < (unsigned)LLEN)
            v = (ci < CCOND) ? cin[((size_t)b * CCOND + ci) * LLEN + g]
                             : xin[((size_t)b * CX + (ci - CCOND)) * LLEN + g];
        bufA[pos * RSTR + ci] = f2bf(v);
    }
    for (int p = tid; p < ROWS; p += NT)
        *reinterpret_cast<uint4*>(&bufA[p * RSTR + 24]) = make_uint4(0, 0, 0, 0);
    __syncthreads();

    unsigned short* bin = bufA;
    unsigned short* bout = bufB;
    float vs[8] = {0.f, 0.f, 0.f, 0.f, 0.f, 0.f, 0.f, 0.f};  // [mt][r] mean acc

    for (int l = 0; l < 4; ++l) {
        const unsigned short* wl = wf + l * 3072;
        bf16x8 af[3][2];
        #pragma unroll
        for (int s = 0; s < 3; ++s)
            #pragma unroll
            for (int mt = 0; mt < 2; ++mt)
                af[s][mt] = *reinterpret_cast<const bf16x8*>(
                    wl + ((s * 2 + mt) << 9) + (lane << 3));
        const float* bp = (l == 0) ? b0p : bhp + (l - 1) * HID;
        f32x4 bias0 = *reinterpret_cast<const f32x4*>(bp + co0);
        f32x4 bias1 = *reinterpret_cast<const f32x4*>(bp + 16 + co0);

        // 17 N-tiles (272 computed positions) over 4 waves
        for (int nt = wv; nt <= 16; nt += 4) {
            const int o = 1 + nt * 16 + prow;        // output row in window
            f32x4 a0 = bias0, a1 = bias1;
            #pragma unroll
            for (int s = 0; s < 3; ++s) {
                bf16x8 bfr = *reinterpret_cast<const bf16x8*>(
                    &bin[(o + s - 1) * RSTR + ci0]);
                a0 = __builtin_amdgcn_mfma_f32_16x16x32_bf16(af[s][0], bfr, a0, 0, 0, 0);
                a1 = __builtin_amdgcn_mfma_f32_16x16x32_bf16(af[s][1], bfr, a1, 0, 0, 0);
            }
            #pragma unroll
            for (int r = 0; r < 4; ++r) {
                a0[r] = fmaxf(a0[r], 0.f);
                a1[r] = fmaxf(a1[r], 0.f);
            }
            if (l < 3) {
                unsigned lo0 = f2bf(a0[0]) | ((unsigned)f2bf(a0[1]) << 16);
                unsigned hi0 = f2bf(a0[2]) | ((unsigned)f2bf(a0[3]) << 16);
                *reinterpret_cast<uint2*>(&bout[o * RSTR + co0]) = make_uint2(lo0, hi0);
                unsigned lo1 = f2bf(a1[0]) | ((unsigned)f2bf(a1[1]) << 16);
                unsigned hi1 = f2bf(a1[2]) | ((unsigned)f2bf(a1[3]) << 16);
                *reinterpret_cast<uint2*>(&bout[o * RSTR + 16 + co0]) = make_uint2(lo1, hi1);
            } else if (o >= 5 && o < 5 + TILE) {      // valid tile rows only
                #pragma unroll
                for (int r = 0; r < 4; ++r) { vs[r] += a0[r]; vs[4 + r] += a1[r]; }
            }
        }
        if (l < 3) {
            __syncthreads();
            unsigned short* tmp = bin; bin = bout; bout = tmp;
        }
    }

    // reduce vs over the 16 position-lanes (co fixed within each xor group)
    #pragma unroll
    for (int off = 1; off < 16; off <<= 1)
        #pragma unroll
        for (int r = 0; r < 8; ++r)
            vs[r] += __shfl_xor(vs[r], off, 64);
    if (prow == 0) {
        #pragma unroll
        for (int r = 0; r < 4; ++r) {
            atomicAdd(&hbar[b * HID + co0 + r], vs[r]);
            atomicAdd(&hbar[b * HID + 16 + co0 + r], vs[4 + r]);
        }
    }
}

// ---------------------------------------------------------------- spline prep
__device__ __forceinline__ float softplusf(float v) {
    return fmaxf(v, 0.f) + log1pf(expf(-fabsf(v)));
}

// One thread per (b,c): p = w_out * mean(h) + b_out, then knot arrays.
// Record layout (stride PSTR): cw[0..8], ch[9..17], w[18..25], h[26..33], d[34..42]
__global__ void params_kernel(const float* __restrict__ hbar,   // [B][32] sums
                              const float* __restrict__ w_out,  // [184][32] for this t
                              const float* __restrict__ b_out,  // [184]
                              float* __restrict__ params) {
    int tg = blockIdx.x * 256 + threadIdx.x;
    if (tg >= BATCH * CX) return;
    int b = tg >> 3, c = tg & 7;
    const float invL = 1.0f / (float)LLEN;

    float hb[HID];
    #pragma unroll
    for (int h = 0; h < HID; h++) hb[h] = hbar[b * HID + h] * invL;

    float p[PDIM];
    #pragma unroll
    for (int j = 0; j < PDIM; j++) {
        int cp = c * PDIM + j;
        float acc = b_out[cp];
        #pragma unroll
        for (int h = 0; h < HID; h++) acc = fmaf(w_out[cp * HID + h], hb[h], acc);
        p[j] = acc;
    }

    float* out = params + (size_t)tg * PSTR;

    // widths -> knot x positions
    {
        float mx = p[0];
        #pragma unroll
        for (int k = 1; k < 8; k++) mx = fmaxf(mx, p[k]);
        float e[8], se = 0.f;
        #pragma unroll
        for (int k = 0; k < 8; k++) { e[k] = expf(p[k] - mx); se += e[k]; }
        float inv = 1.f / se, cum = 0.f;
        float cw[9]; cw[0] = -3.f;
        #pragma unroll
        for (int k = 0; k < 8; k++) {
            float wk = 1e-3f + (1.f - 8e-3f) * (e[k] * inv);
            cum += wk;
            cw[k + 1] = 6.f * cum - 3.f;
        }
        #pragma unroll
        for (int k = 0; k < 9; k++) out[k] = cw[k];
        #pragma unroll
        for (int k = 0; k < 8; k++) out[18 + k] = cw[k + 1] - cw[k];
    }
    // heights -> knot y positions
    {
        float mx = p[8];
        #pragma unroll
        for (int k = 1; k < 8; k++) mx = fmaxf(mx, p[8 + k]);
        float e[8], se = 0.f;
        #pragma unroll
        for (int k = 0; k < 8; k++) { e[k] = expf(p[8 + k] - mx); se += e[k]; }
        float inv = 1.f / se, cum = 0.f;
        float ch[9]; ch[0] = -3.f;
        #pragma unroll
        for (int k = 0; k < 8; k++) {
            float hk = 1e-3f + (1.f - 8e-3f) * (e[k] * inv);
            cum += hk;
            ch[k + 1] = 6.f * cum - 3.f;
        }
        #pragma unroll
        for (int k = 0; k < 9; k++) out[9 + k] = ch[k];
        #pragma unroll
        for (int k = 0; k < 8; k++) out[26 + k] = ch[k + 1] - ch[k];
    }
    // derivatives (boundary = 1)
    out[34] = 1.f;
    #pragma unroll
    for (int k = 0; k < 7; k++) out[35 + k] = 1e-3f + softplusf(p[16 + k]);
    out[42] = 1.f;
}

// ---------------------------------------------------------------- RQS inverse
__global__ __launch_bounds__(256) void rqs_kernel(const float* __restrict__ params,
                                                  float* __restrict__ x,
                                                  float* __restrict__ logdet) {
    __shared__ float pr[43];
    __shared__ float red[4];
    const int bc = blockIdx.y;
    const int tid = threadIdx.x;
    if (tid < 43) pr[tid] = params[(size_t)bc * PSTR + tid];
    __syncthreads();

    const float* cw = pr;
    const float* ch = pr + 9;
    const float* wd = pr + 18;
    const float* hg = pr + 26;
    const float* dv = pr + 34;

    int pos = blockIdx.x * 256 + tid;
    size_t xi = (size_t)bc * LLEN + pos;
    float y = x[xi];
    bool inside = fabsf(y) <= 3.0f;
    float yc = fminf(fmaxf(y, -3.f), 3.f);

    int idx = 0;
    #pragma unroll
    for (int k = 1; k < 9; k++) idx += (yc >= ch[k]) ? 1 : 0;
    idx = idx > 7 ? 7 : idx;

    float icw = cw[idx], iw = wd[idx], ich = ch[idx], ih = hg[idx];
    float dk = dv[idx], dk1 = dv[idx + 1];

    float s  = ih / iw;
    float dy = yc - ich;
    float t1 = dk + dk1 - 2.f * s;
    float a  = ih * (s - dk) + dy * t1;
    float bq = ih * dk - dy * t1;
    float cq = -s * dy;
    float disc = fmaxf(bq * bq - 4.f * a * cq, 0.f);
    float root = (2.f * cq) / (-bq - sqrtf(disc));
    float om = 1.f - root;
    float outv  = fmaf(root, iw, icw);
    float denom = fmaf(t1 * root, om, s);
    float dnum  = s * s * (dk1 * root * root + 2.f * s * root * om + dk * om * om);
    float ld = 2.f * logf(denom) - logf(dnum);   // = -(log dnum - 2 log denom)

    x[xi] = inside ? outv : y;
    float ldv = inside ? ld : 0.f;

    #pragma unroll
    for (int off = 32; off > 0; off >>= 1) ldv += __shfl_xor(ldv, off, 64);
    if ((tid & 63) == 0) red[tid >> 6] = ldv;
    __syncthreads();
    if (tid == 0) {
        float sb = red[0] + red[1] + red[2] + red[3];
        atomicAdd(&logdet[bc >> 3], sb * (1.0f / (float)LLEN));
    }
}

// ---------------------------------------------------------------- launch
extern "C" void kernel_launch(void* const* d_in, const int* in_sizes, int n_in,
                              void* d_out, int out_size, void* d_ws, size_t ws_size,
                              hipStream_t stream) {
    const float* cin   = (const float*)d_in[1];
    const float* noise = (const float*)d_in[2];
    const float* w0    = (const float*)d_in[3];
    const float* b0    = (const float*)d_in[4];
    const float* wh    = (const float*)d_in[5];
    const float* bh    = (const float*)d_in[6];
    const float* w_out = (const float*)d_in[7];
    const float* b_out = (const float*)d_in[8];

    float* xout   = (float*)d_out;                       // [128*8*8192]
    float* logdet = xout + (size_t)BATCH * CX * LLEN;    // [128]

    float* ws     = (float*)d_ws;
    float* hbar   = ws;                                  // 4096 floats
    float* params = ws + 4096;                           // 1024*48 floats
    unsigned short* wf = (unsigned short*)(ws + 4096 + 1024 * PSTR);  // 24576 ushorts

    const int nx = BATCH * CX * LLEN;                    // 8388608
    init_kernel<<<nx / 256, 256, 0, stream>>>(noise, xout, logdet);
    repack_frag_kernel<<<96, 256, 0, stream>>>(w0, wh, wf);

    for (int t = 0; t < NSTEP; t++) {
        zero_kernel<<<(BATCH * HID + 255) / 256, 256, 0, stream>>>(hbar, BATCH * HID);
        conv_kernel<<<dim3(LLEN / TILE, BATCH), 256, 0, stream>>>(
            cin, xout,
            wf + t * 12288, b0 + t * HID, bh + t * 3 * HID,
            hbar);
        params_kernel<<<(BATCH * CX + 255) / 256, 256, 0, stream>>>(
            hbar, w_out + t * POUT * HID, b_out + t * POUT, params);
        rqs_kernel<<<dim3(LLEN / TILE, BATCH * CX), 256, 0, stream>>>(params, xout, logdet);
    }
}

// Round 3
// 439.426 us; speedup vs baseline: 3.2803x; 1.6288x over previous
//
#include <hip/hip_runtime.h>
#include <hip/hip_bf16.h>

// Sizes (fixed by the problem)
#define BATCH 128
#define CCOND 16          // conditioning channels
#define CX    8           // flow channels
#define CIN0  24          // CCOND + CX
#define HID   32
#define LLEN  8192
#define NSTEP 2
#define PDIM  23          // 3K-1, K=8
#define POUT  184         // PDIM * CX
#define PSTR  48          // per-(b,c) param record stride in ws

// conv tiling
#define TILE  256         // valid output positions per block
#define ROWS  276         // staged rows: global g in [gbase-5, gbase+271)
#define RSTR  40          // bf16 stride per row (80 B)
#define NT    256

typedef __bf16 bf16x8 __attribute__((ext_vector_type(8)));
typedef __bf16 bf16x4 __attribute__((ext_vector_type(4)));
typedef float  f32x4  __attribute__((ext_vector_type(4)));

__device__ __forceinline__ unsigned short f2bf(float f) {
    unsigned u = __float_as_uint(f);
    return (unsigned short)((u + 0x7FFFu + ((u >> 16) & 1u)) >> 16);
}

// ---------------------------------------------------------------- util
__global__ void zero_kernel(float* __restrict__ p, int n) {
    int i = blockIdx.x * 256 + threadIdx.x;
    if (i < n) p[i] = 0.f;
}

// Pack conv weights into exact per-lane MFMA A-fragment order (bf16).
// wf[t][layer][s][mt][lane][j]; element = W[co = mt*16+(lane&15)]
//                                          [ci = (lane>>4)*8+j][koff = s]
__global__ void repack_frag_kernel(const float* __restrict__ w0,   // [2][32][24][3]
                                   const float* __restrict__ wh,   // [2][3][32][32][3]
                                   unsigned short* __restrict__ wf) {
    int i = blockIdx.x * 256 + threadIdx.x;     // 24576 total
    int j = i & 7, lane = (i >> 3) & 63, q = i >> 9;
    int mt = q & 1; q >>= 1;
    int s = q % 3;  q /= 3;
    int l = q & 3, t = q >> 2;
    int m = mt * 16 + (lane & 15);
    int ci = (lane >> 4) * 8 + j;
    float v;
    if (l == 0)
        v = (ci < CIN0) ? w0[((t * HID + m) * CIN0 + ci) * 3 + s] : 0.f;
    else
        v = wh[(((t * 3 + (l - 1)) * HID + m) * HID + ci) * 3 + s];
    wf[i] = f2bf(v);
}

// ---------------------------------------------------------------- fused convs
__global__ __launch_bounds__(256) void conv_kernel(
        const float* __restrict__ cin,   // [B][16][L]
        const float* __restrict__ xin,   // [B][8][L]
        const unsigned short* __restrict__ wf,  // this t: [4][3][2][64][8]
        const float* __restrict__ b0p,   // [32]   (this t)
        const float* __restrict__ bhp,   // [3][32](this t)
        float* __restrict__ hbar) {      // [B][32] sums (atomic)
    __shared__ __align__(16) __bf16 bufA[ROWS * RSTR];
    __shared__ __align__(16) __bf16 bufB[ROWS * RSTR];

    const int b = blockIdx.y;
    const int gbase = blockIdx.x * TILE;
    const int tid = threadIdx.x;
    const int lane = tid & 63, wv = tid >> 6;
    const int prow = lane & 15;          // position within N-tile (D col)
    const int grp  = lane >> 4;          // 0..3
    const int ci0  = grp * 8;            // B-frag channel chunk
    const int co0  = grp * 4;            // D row base within M-tile

    // stage 24 input channels as bf16; channels 24..31 zeroed (K padding)
    for (int e = tid; e < CIN0 * ROWS; e += NT) {
        int ci = e / ROWS, pos = e - ci * ROWS;
        int g = gbase - 5 + pos;
        float v = 0.f;
        if ((unsigned)g < (unsigned)LLEN)
            v = (ci < CCOND) ? cin[((size_t)b * CCOND + ci) * LLEN + g]
                             : xin[((size_t)b * CX + (ci - CCOND)) * LLEN + g];
        bufA[pos * RSTR + ci] = (__bf16)v;
    }
    for (int p = tid; p < ROWS; p += NT)
        *reinterpret_cast<uint4*>(&bufA[p * RSTR + 24]) = make_uint4(0, 0, 0, 0);
    __syncthreads();

    __bf16* bin = bufA;
    __bf16* bout = bufB;
    float vs[8] = {0.f, 0.f, 0.f, 0.f, 0.f, 0.f, 0.f, 0.f};  // [mt][r] mean acc

    for (int l = 0; l < 4; ++l) {
        const unsigned short* wl = wf + l * 3072;
        bf16x8 af[3][2];
        #pragma unroll
        for (int s = 0; s < 3; ++s)
            #pragma unroll
            for (int mt = 0; mt < 2; ++mt)
                af[s][mt] = *reinterpret_cast<const bf16x8*>(
                    wl + ((s * 2 + mt) << 9) + (lane << 3));
        const float* bp = (l == 0) ? b0p : bhp + (l - 1) * HID;
        f32x4 bias0 = *reinterpret_cast<const f32x4*>(bp + co0);
        f32x4 bias1 = *reinterpret_cast<const f32x4*>(bp + 16 + co0);

        // 17 N-tiles (272 computed positions) over 4 waves
        for (int nt = wv; nt <= 16; nt += 4) {
            const int o = 1 + nt * 16 + prow;        // output row in window
            f32x4 a0 = bias0, a1 = bias1;
            #pragma unroll
            for (int s = 0; s < 3; ++s) {
                bf16x8 bfr = *reinterpret_cast<const bf16x8*>(
                    &bin[(o + s - 1) * RSTR + ci0]);
                a0 = __builtin_amdgcn_mfma_f32_16x16x32_bf16(af[s][0], bfr, a0, 0, 0, 0);
                a1 = __builtin_amdgcn_mfma_f32_16x16x32_bf16(af[s][1], bfr, a1, 0, 0, 0);
            }
            #pragma unroll
            for (int r = 0; r < 4; ++r) {
                a0[r] = fmaxf(a0[r], 0.f);
                a1[r] = fmaxf(a1[r], 0.f);
            }
            if (l < 3) {
                bf16x4 p0, p1;
                #pragma unroll
                for (int r = 0; r < 4; ++r) { p0[r] = (__bf16)a0[r]; p1[r] = (__bf16)a1[r]; }
                *reinterpret_cast<bf16x4*>(&bout[o * RSTR + co0]) = p0;
                *reinterpret_cast<bf16x4*>(&bout[o * RSTR + 16 + co0]) = p1;
            } else if (o >= 5 && o < 5 + TILE) {      // valid tile rows only
                #pragma unroll
                for (int r = 0; r < 4; ++r) { vs[r] += a0[r]; vs[4 + r] += a1[r]; }
            }
        }
        if (l < 3) {
            __syncthreads();
            __bf16* tmp = bin; bin = bout; bout = tmp;
        }
    }

    // reduce vs over the 16 position-lanes (co fixed within each xor group)
    #pragma unroll
    for (int off = 1; off < 16; off <<= 1)
        #pragma unroll
        for (int r = 0; r < 8; ++r)
            vs[r] += __shfl_xor(vs[r], off, 64);
    if (prow == 0) {
        #pragma unroll
        for (int r = 0; r < 4; ++r) {
            atomicAdd(&hbar[b * HID + co0 + r], vs[r]);
            atomicAdd(&hbar[b * HID + 16 + co0 + r], vs[4 + r]);
        }
    }
}

// ---------------------------------------------------------------- spline prep
__device__ __forceinline__ float softplusf(float v) {
    return fmaxf(v, 0.f) + log1pf(expf(-fabsf(v)));
}

// One thread per (b,c): p = w_out * mean(h) + b_out, then knot arrays.
// Record layout (stride PSTR): cw[0..8], ch[9..17], w[18..25], h[26..33], d[34..42]
__global__ void params_kernel(const float* __restrict__ hbar,   // [B][32] sums
                              const float* __restrict__ w_out,  // [184][32] for this t
                              const float* __restrict__ b_out,  // [184]
                              float* __restrict__ params) {
    int tg = blockIdx.x * 256 + threadIdx.x;
    if (tg >= BATCH * CX) return;
    int b = tg >> 3, c = tg & 7;
    const float invL = 1.0f / (float)LLEN;

    float hb[HID];
    #pragma unroll
    for (int h = 0; h < HID; h++) hb[h] = hbar[b * HID + h] * invL;

    float p[PDIM];
    #pragma unroll
    for (int j = 0; j < PDIM; j++) {
        int cp = c * PDIM + j;
        float acc = b_out[cp];
        #pragma unroll
        for (int h = 0; h < HID; h++) acc = fmaf(w_out[cp * HID + h], hb[h], acc);
        p[j] = acc;
    }

    float* out = params + (size_t)tg * PSTR;

    // widths -> knot x positions
    {
        float mx = p[0];
        #pragma unroll
        for (int k = 1; k < 8; k++) mx = fmaxf(mx, p[k]);
        float e[8], se = 0.f;
        #pragma unroll
        for (int k = 0; k < 8; k++) { e[k] = expf(p[k] - mx); se += e[k]; }
        float inv = 1.f / se, cum = 0.f;
        float cw[9]; cw[0] = -3.f;
        #pragma unroll
        for (int k = 0; k < 8; k++) {
            float wk = 1e-3f + (1.f - 8e-3f) * (e[k] * inv);
            cum += wk;
            cw[k + 1] = 6.f * cum - 3.f;
        }
        #pragma unroll
        for (int k = 0; k < 9; k++) out[k] = cw[k];
        #pragma unroll
        for (int k = 0; k < 8; k++) out[18 + k] = cw[k + 1] - cw[k];
    }
    // heights -> knot y positions
    {
        float mx = p[8];
        #pragma unroll
        for (int k = 1; k < 8; k++) mx = fmaxf(mx, p[8 + k]);
        float e[8], se = 0.f;
        #pragma unroll
        for (int k = 0; k < 8; k++) { e[k] = expf(p[8 + k] - mx); se += e[k]; }
        float inv = 1.f / se, cum = 0.f;
        float ch[9]; ch[0] = -3.f;
        #pragma unroll
        for (int k = 0; k < 8; k++) {
            float hk = 1e-3f + (1.f - 8e-3f) * (e[k] * inv);
            cum += hk;
            ch[k + 1] = 6.f * cum - 3.f;
        }
        #pragma unroll
        for (int k = 0; k < 9; k++) out[9 + k] = ch[k];
        #pragma unroll
        for (int k = 0; k < 8; k++) out[26 + k] = ch[k + 1] - ch[k];
    }
    // derivatives (boundary = 1)
    out[34] = 1.f;
    #pragma unroll
    for (int k = 0; k < 7; k++) out[35 + k] = 1e-3f + softplusf(p[16 + k]);
    out[42] = 1.f;
}

// ---------------------------------------------------------------- RQS inverse
// 4 elements/thread (float4). Params are wave-uniform -> SGPRs; bin gather is
// a branchless cndmask select tree; transcendentals are raw v_log/v_sqrt/v_rcp.
__global__ __launch_bounds__(256) void rqs_kernel(const float* __restrict__ params,
                                                  const float* __restrict__ xin,
                                                  float* __restrict__ xout,
                                                  float* __restrict__ logdet) {
    const int bc = blockIdx.y;
    const float* __restrict__ pp = params + (size_t)bc * PSTR;
    float cw[9], chv[9], wd[8], hg[8], dv[9];
    #pragma unroll
    for (int k = 0; k < 9; k++) cw[k] = pp[k];
    #pragma unroll
    for (int k = 0; k < 9; k++) chv[k] = pp[9 + k];
    #pragma unroll
    for (int k = 0; k < 8; k++) wd[k] = pp[18 + k];
    #pragma unroll
    for (int k = 0; k < 8; k++) hg[k] = pp[26 + k];
    #pragma unroll
    for (int k = 0; k < 9; k++) dv[k] = pp[34 + k];

    const int tid = threadIdx.x;
    size_t base = (size_t)bc * LLEN + (size_t)(blockIdx.x * 256 + tid) * 4;
    float4 y4 = *reinterpret_cast<const float4*>(xin + base);
    float yv[4] = {y4.x, y4.y, y4.z, y4.w};
    float ov[4];
    float ldsum = 0.f;

    #pragma unroll
    for (int j = 0; j < 4; j++) {
        float y = yv[j];
        bool inside = fabsf(y) <= 3.0f;
        float yc = fminf(fmaxf(y, -3.f), 3.f);

        float icw = cw[0], iw = wd[0], ich = chv[0], ih = hg[0];
        float dk = dv[0], dk1 = dv[1];
        #pragma unroll
        for (int k = 1; k < 8; k++) {
            bool c = yc >= chv[k];
            icw = c ? cw[k]  : icw;
            iw  = c ? wd[k]  : iw;
            ich = c ? chv[k] : ich;
            ih  = c ? hg[k]  : ih;
            dk  = c ? dv[k]  : dk;
            dk1 = c ? dv[k + 1] : dk1;
        }

        float s  = ih * __builtin_amdgcn_rcpf(iw);
        float dy = yc - ich;
        float t1 = dk + dk1 - 2.f * s;
        float a  = ih * (s - dk) + dy * t1;
        float bq = ih * dk - dy * t1;
        float cq = -s * dy;
        float disc = fmaxf(bq * bq - 4.f * a * cq, 0.f);
        float den  = -bq - __builtin_amdgcn_sqrtf(disc);
        float root = (2.f * cq) * __builtin_amdgcn_rcpf(den);
        float om = 1.f - root;
        float outv  = fmaf(root, iw, icw);
        float denom = fmaf(t1 * root, om, s);
        float dnum  = s * s * (dk1 * root * root + 2.f * s * root * om + dk * om * om);
        float ld = (2.f * __builtin_amdgcn_logf(denom) - __builtin_amdgcn_logf(dnum))
                   * 0.69314718055994531f;
        ov[j] = inside ? outv : y;
        ldsum += inside ? ld : 0.f;
    }

    *reinterpret_cast<float4*>(xout + base) = make_float4(ov[0], ov[1], ov[2], ov[3]);

    #pragma unroll
    for (int off = 32; off > 0; off >>= 1) ldsum += __shfl_xor(ldsum, off, 64);
    __shared__ float red[4];
    if ((tid & 63) == 0) red[tid >> 6] = ldsum;
    __syncthreads();
    if (tid == 0) {
        float sb = red[0] + red[1] + red[2] + red[3];
        atomicAdd(&logdet[bc >> 3], sb * (1.0f / (float)LLEN));
    }
}

// ---------------------------------------------------------------- launch
extern "C" void kernel_launch(void* const* d_in, const int* in_sizes, int n_in,
                              void* d_out, int out_size, void* d_ws, size_t ws_size,
                              hipStream_t stream) {
    const float* cin   = (const float*)d_in[1];
    const float* noise = (const float*)d_in[2];
    const float* w0    = (const float*)d_in[3];
    const float* b0    = (const float*)d_in[4];
    const float* wh    = (const float*)d_in[5];
    const float* bh    = (const float*)d_in[6];
    const float* w_out = (const float*)d_in[7];
    const float* b_out = (const float*)d_in[8];

    float* xout   = (float*)d_out;                       // [128*8*8192]
    float* logdet = xout + (size_t)BATCH * CX * LLEN;    // [128]

    float* ws     = (float*)d_ws;
    float* hbar   = ws;                                  // 4096 floats
    float* params = ws + 4096;                           // 1024*48 floats
    unsigned short* wf = (unsigned short*)(ws + 4096 + 1024 * PSTR);  // 24576 ushorts

    zero_kernel<<<1, 256, 0, stream>>>(logdet, BATCH);
    repack_frag_kernel<<<96, 256, 0, stream>>>(w0, wh, wf);

    for (int t = 0; t < NSTEP; t++) {
        const float* xcur = (t == 0) ? noise : xout;
        zero_kernel<<<(BATCH * HID + 255) / 256, 256, 0, stream>>>(hbar, BATCH * HID);
        conv_kernel<<<dim3(LLEN / TILE, BATCH), 256, 0, stream>>>(
            cin, xcur,
            wf + t * 12288, b0 + t * HID, bh + t * 3 * HID,
            hbar);
        params_kernel<<<(BATCH * CX + 255) / 256, 256, 0, stream>>>(
            hbar, w_out + t * POUT * HID, b_out + t * POUT, params);
        rqs_kernel<<<dim3(LLEN / (256 * 4), BATCH * CX), 256, 0, stream>>>(
            params, xcur, xout, logdet);
    }
}

// Round 4
// 367.316 us; speedup vs baseline: 3.9242x; 1.1963x over previous
//
#include <hip/hip_runtime.h>
#include <hip/hip_bf16.h>

// Sizes (fixed by the problem)
#define BATCH 128
#define CCOND 16          // conditioning channels
#define CX    8           // flow channels
#define CIN0  24          // CCOND + CX
#define HID   32
#define LLEN  8192
#define NSTEP 2
#define PDIM  23          // 3K-1, K=8
#define POUT  184         // PDIM * CX
#define PSTR  48          // per-(b,c) param record stride in ws

// conv tiling
#define TILE   128        // valid output positions per block
#define NT     256
#define ROWS   148        // staged window [gbase-8, gbase+140)
#define RSTR   40         // bf16 stride per row (80 B, 16B-aligned chunks)
#define NTILES 9          // o = 3 + nt*16 + prow, o in [3,147)
#define QUADS  37         // ROWS/4
#define SUNITS (6 * QUADS * 4)   // 6 ch-blocks x 37 quads x 4 lanes = 888

typedef __bf16 bf16x8 __attribute__((ext_vector_type(8)));
typedef __bf16 bf16x4 __attribute__((ext_vector_type(4)));
typedef float  f32x4  __attribute__((ext_vector_type(4)));

__device__ __forceinline__ unsigned short f2bf(float f) {
    unsigned u = __float_as_uint(f);
    return (unsigned short)((u + 0x7FFFu + ((u >> 16) & 1u)) >> 16);
}

// ---------------------------------------------------------------- util
// zeros hbar0|hbar1 (ws[0..8192)) and logdet[0..128)
__global__ void zero_kernel(float* __restrict__ ws, float* __restrict__ logdet) {
    int i = blockIdx.x * 256 + threadIdx.x;
    ws[i] = 0.f;
    if (i < BATCH) logdet[i] = 0.f;
}

// Pack conv weights into exact per-lane MFMA A-fragment order (bf16).
// wf[t][layer][s][mt][lane][j]; element = W[co = mt*16+(lane&15)]
//                                          [ci = (lane>>4)*8+j][koff = s]
__global__ void repack_frag_kernel(const float* __restrict__ w0,   // [2][32][24][3]
                                   const float* __restrict__ wh,   // [2][3][32][32][3]
                                   unsigned short* __restrict__ wf) {
    int i = blockIdx.x * 256 + threadIdx.x;     // 24576 total
    int j = i & 7, lane = (i >> 3) & 63, q = i >> 9;
    int mt = q & 1; q >>= 1;
    int s = q % 3;  q /= 3;
    int l = q & 3, t = q >> 2;
    int m = mt * 16 + (lane & 15);
    int ci = (lane >> 4) * 8 + j;
    float v;
    if (l == 0)
        v = (ci < CIN0) ? w0[((t * HID + m) * CIN0 + ci) * 3 + s] : 0.f;
    else
        v = wh[(((t * 3 + (l - 1)) * HID + m) * HID + ci) * 3 + s];
    wf[i] = f2bf(v);
}

// ---------------------------------------------------------------- fused convs
// One conv layer over the whole window. bin rows [o-1,o+1] -> bout row o,
// o = 3 + nt*16 + prow for nt in [0,9). LAST: accumulate L-mean instead.
template<int LAST>
__device__ __forceinline__ void conv_layer(
        const __bf16* __restrict__ bin, __bf16* __restrict__ bout,
        const unsigned short* __restrict__ wl, const float* __restrict__ bp,
        int lane, int wv, float* __restrict__ vs) {
    const int prow = lane & 15, grp = lane >> 4;
    const int ci0 = grp * 8, co0 = grp * 4;

    bf16x8 af[3][2];
    #pragma unroll
    for (int s = 0; s < 3; ++s)
        #pragma unroll
        for (int mt = 0; mt < 2; ++mt)
            af[s][mt] = *reinterpret_cast<const bf16x8*>(
                wl + ((s * 2 + mt) << 9) + (lane << 3));
    f32x4 bias0 = *reinterpret_cast<const f32x4*>(bp + co0);
    f32x4 bias1 = *reinterpret_cast<const f32x4*>(bp + 16 + co0);

    for (int nt = wv; nt < NTILES; nt += 4) {
        const int o = 3 + nt * 16 + prow;
        bf16x8 bf0 = *reinterpret_cast<const bf16x8*>(&bin[(o - 1) * RSTR + ci0]);
        bf16x8 bf1 = *reinterpret_cast<const bf16x8*>(&bin[(o    ) * RSTR + ci0]);
        bf16x8 bf2 = *reinterpret_cast<const bf16x8*>(&bin[(o + 1) * RSTR + ci0]);
        f32x4 a0 = bias0, a1 = bias1;
        a0 = __builtin_amdgcn_mfma_f32_16x16x32_bf16(af[0][0], bf0, a0, 0, 0, 0);
        a1 = __builtin_amdgcn_mfma_f32_16x16x32_bf16(af[0][1], bf0, a1, 0, 0, 0);
        a0 = __builtin_amdgcn_mfma_f32_16x16x32_bf16(af[1][0], bf1, a0, 0, 0, 0);
        a1 = __builtin_amdgcn_mfma_f32_16x16x32_bf16(af[1][1], bf1, a1, 0, 0, 0);
        a0 = __builtin_amdgcn_mfma_f32_16x16x32_bf16(af[2][0], bf2, a0, 0, 0, 0);
        a1 = __builtin_amdgcn_mfma_f32_16x16x32_bf16(af[2][1], bf2, a1, 0, 0, 0);
        #pragma unroll
        for (int r = 0; r < 4; ++r) {
            a0[r] = fmaxf(a0[r], 0.f);
            a1[r] = fmaxf(a1[r], 0.f);
        }
        if (!LAST) {
            bf16x4 p0, p1;
            #pragma unroll
            for (int r = 0; r < 4; ++r) { p0[r] = (__bf16)a0[r]; p1[r] = (__bf16)a1[r]; }
            *reinterpret_cast<bf16x4*>(&bout[o * RSTR + co0]) = p0;
            *reinterpret_cast<bf16x4*>(&bout[o * RSTR + 16 + co0]) = p1;
        } else if (o >= 8 && o < 8 + TILE) {
            #pragma unroll
            for (int r = 0; r < 4; ++r) { vs[r] += a0[r]; vs[4 + r] += a1[r]; }
        }
    }
}

__global__ __launch_bounds__(256, 5) void conv_kernel(
        const float* __restrict__ cin,   // [B][16][L]
        const float* __restrict__ xin,   // [B][8][L]
        const unsigned short* __restrict__ wf,  // this t: [4][3][2][64][8]
        const float* __restrict__ b0p,   // [32]   (this t)
        const float* __restrict__ bhp,   // [3][32](this t)
        float* __restrict__ hbar) {      // [B][32] sums (atomic)
    __shared__ __align__(16) __bf16 bufA[ROWS * RSTR];
    __shared__ __align__(16) __bf16 bufB[ROWS * RSTR];

    const int b = blockIdx.y;
    const int gbase = blockIdx.x * TILE;
    const int tid = threadIdx.x;
    const int lane = tid & 63, wv = tid >> 6;
    const int sub = tid & 3;

    // ---- staging: coalesced float4 loads, 4x4 lane transpose, b64 LDS writes
    for (int u = tid; u < SUNITS; u += NT) {
        int g4 = u >> 2;                  // group: 4 lanes = 4 channels x 4 pos
        int qq = g4 % QUADS, cb = g4 / QUADS;
        int ch = cb * 4 + sub;
        int gg = gbase - 8 + qq * 4;
        float4 f = make_float4(0.f, 0.f, 0.f, 0.f);
        if ((unsigned)gg < (unsigned)LLEN) {
            const float* src = (ch < CCOND)
                ? cin + ((size_t)b * CCOND + ch) * LLEN
                : xin + ((size_t)b * CX + (ch - CCOND)) * LLEN;
            f = *reinterpret_cast<const float4*>(src + gg);
        }
        // transpose within the 4-lane group: lane ends with 4 channels @ 1 pos
        float tv0 = 0.f, tv1 = 0.f, tv2 = 0.f, tv3 = 0.f;
        #pragma unroll
        for (int r = 0; r < 4; ++r) {
            int ksel = (sub - r) & 3;
            float x = ksel == 0 ? f.x : ksel == 1 ? f.y : ksel == 2 ? f.z : f.w;
            int j = (sub + r) & 3;
            float v = __shfl(x, (lane & ~3) | j, 64);
            tv0 = (j == 0) ? v : tv0;
            tv1 = (j == 1) ? v : tv1;
            tv2 = (j == 2) ? v : tv2;
            tv3 = (j == 3) ? v : tv3;
        }
        int p = qq * 4 + sub;
        bf16x4 pk;
        pk[0] = (__bf16)tv0; pk[1] = (__bf16)tv1;
        pk[2] = (__bf16)tv2; pk[3] = (__bf16)tv3;
        *reinterpret_cast<bf16x4*>(&bufA[p * RSTR + cb * 4]) = pk;
    }
    // zero K-padding channels 24..31
    for (int p = tid; p < ROWS; p += NT)
        *reinterpret_cast<uint4*>(&bufA[p * RSTR + 24]) = make_uint4(0, 0, 0, 0);
    __syncthreads();

    float vs[8] = {0.f, 0.f, 0.f, 0.f, 0.f, 0.f, 0.f, 0.f};
    conv_layer<0>(bufA, bufB, wf,        b0p,      lane, wv, vs);
    __syncthreads();
    conv_layer<0>(bufB, bufA, wf + 3072, bhp,      lane, wv, vs);
    __syncthreads();
    conv_layer<0>(bufA, bufB, wf + 6144, bhp + 32, lane, wv, vs);
    __syncthreads();
    conv_layer<1>(bufB, bufA, wf + 9216, bhp + 64, lane, wv, vs);

    // reduce vs over the 16 position-lanes (co fixed within each xor group)
    #pragma unroll
    for (int off = 1; off < 16; off <<= 1)
        #pragma unroll
        for (int r = 0; r < 8; ++r)
            vs[r] += __shfl_xor(vs[r], off, 64);
    const int grp = lane >> 4, co0 = grp * 4;
    if ((lane & 15) == 0) {
        #pragma unroll
        for (int r = 0; r < 4; ++r) {
            atomicAdd(&hbar[b * HID + co0 + r], vs[r]);
            atomicAdd(&hbar[b * HID + 16 + co0 + r], vs[4 + r]);
        }
    }
}

// ---------------------------------------------------------------- spline prep
__device__ __forceinline__ float softplusf(float v) {
    return fmaxf(v, 0.f) + log1pf(expf(-fabsf(v)));
}

// One thread per (b,c): p = w_out * mean(h) + b_out, then knot arrays.
// Record layout (stride PSTR): cw[0..8], ch[9..17], w[18..25], h[26..33], d[34..42]
__global__ void params_kernel(const float* __restrict__ hbar,   // [B][32] sums
                              const float* __restrict__ w_out,  // [184][32] for this t
                              const float* __restrict__ b_out,  // [184]
                              float* __restrict__ params) {
    int tg = blockIdx.x * 256 + threadIdx.x;
    if (tg >= BATCH * CX) return;
    int b = tg >> 3, c = tg & 7;
    const float invL = 1.0f / (float)LLEN;

    float hb[HID];
    #pragma unroll
    for (int h = 0; h < HID; h++) hb[h] = hbar[b * HID + h] * invL;

    float p[PDIM];
    #pragma unroll
    for (int j = 0; j < PDIM; j++) {
        int cp = c * PDIM + j;
        float acc = b_out[cp];
        #pragma unroll
        for (int h = 0; h < HID; h++) acc = fmaf(w_out[cp * HID + h], hb[h], acc);
        p[j] = acc;
    }

    float* out = params + (size_t)tg * PSTR;

    // widths -> knot x positions
    {
        float mx = p[0];
        #pragma unroll
        for (int k = 1; k < 8; k++) mx = fmaxf(mx, p[k]);
        float e[8], se = 0.f;
        #pragma unroll
        for (int k = 0; k < 8; k++) { e[k] = expf(p[k] - mx); se += e[k]; }
        float inv = 1.f / se, cum = 0.f;
        float cw[9]; cw[0] = -3.f;
        #pragma unroll
        for (int k = 0; k < 8; k++) {
            float wk = 1e-3f + (1.f - 8e-3f) * (e[k] * inv);
            cum += wk;
            cw[k + 1] = 6.f * cum - 3.f;
        }
        #pragma unroll
        for (int k = 0; k < 9; k++) out[k] = cw[k];
        #pragma unroll
        for (int k = 0; k < 8; k++) out[18 + k] = cw[k + 1] - cw[k];
    }
    // heights -> knot y positions
    {
        float mx = p[8];
        #pragma unroll
        for (int k = 1; k < 8; k++) mx = fmaxf(mx, p[8 + k]);
        float e[8], se = 0.f;
        #pragma unroll
        for (int k = 0; k < 8; k++) { e[k] = expf(p[8 + k] - mx); se += e[k]; }
        float inv = 1.f / se, cum = 0.f;
        float ch[9]; ch[0] = -3.f;
        #pragma unroll
        for (int k = 0; k < 8; k++) {
            float hk = 1e-3f + (1.f - 8e-3f) * (e[k] * inv);
            cum += hk;
            ch[k + 1] = 6.f * cum - 3.f;
        }
        #pragma unroll
        for (int k = 0; k < 9; k++) out[9 + k] = ch[k];
        #pragma unroll
        for (int k = 0; k < 8; k++) out[26 + k] = ch[k + 1] - ch[k];
    }
    // derivatives (boundary = 1)
    out[34] = 1.f;
    #pragma unroll
    for (int k = 0; k < 7; k++) out[35 + k] = 1e-3f + softplusf(p[16 + k]);
    out[42] = 1.f;
}

// ---------------------------------------------------------------- RQS inverse
// 8 elements/thread (2x float4, hoisted loads). Params wave-uniform -> SGPRs;
// bin gather = branchless cndmask tree; raw v_log/v_sqrt/v_rcp.
__device__ __forceinline__ void rqs_elem(
        const float* cw, const float* chv, const float* wd,
        const float* hg, const float* dv,
        float y, float& ov, float& ldsum) {
    bool inside = fabsf(y) <= 3.0f;
    float yc = fminf(fmaxf(y, -3.f), 3.f);

    float icw = cw[0], iw = wd[0], ich = chv[0], ih = hg[0];
    float dk = dv[0], dk1 = dv[1];
    #pragma unroll
    for (int k = 1; k < 8; k++) {
        bool c = yc >= chv[k];
        icw = c ? cw[k]  : icw;
        iw  = c ? wd[k]  : iw;
        ich = c ? chv[k] : ich;
        ih  = c ? hg[k]  : ih;
        dk  = c ? dv[k]  : dk;
        dk1 = c ? dv[k + 1] : dk1;
    }
    float s  = ih * __builtin_amdgcn_rcpf(iw);
    float dy = yc - ich;
    float t1 = dk + dk1 - 2.f * s;
    float a  = ih * (s - dk) + dy * t1;
    float bq = ih * dk - dy * t1;
    float cq = -s * dy;
    float disc = fmaxf(bq * bq - 4.f * a * cq, 0.f);
    float den  = -bq - __builtin_amdgcn_sqrtf(disc);
    float root = (2.f * cq) * __builtin_amdgcn_rcpf(den);
    float om = 1.f - root;
    float outv  = fmaf(root, iw, icw);
    float denom = fmaf(t1 * root, om, s);
    float dnum  = s * s * (dk1 * root * root + 2.f * s * root * om + dk * om * om);
    float ld = (2.f * __builtin_amdgcn_logf(denom) - __builtin_amdgcn_logf(dnum))
               * 0.69314718055994531f;
    ov = inside ? outv : y;
    ldsum += inside ? ld : 0.f;
}

__global__ __launch_bounds__(256) void rqs_kernel(const float* __restrict__ params,
                                                  const float* __restrict__ xin,
                                                  float* __restrict__ xout,
                                                  float* __restrict__ logdet) {
    const int bc = blockIdx.y;
    const float* __restrict__ pp = params + (size_t)bc * PSTR;
    float cw[9], chv[9], wd[8], hg[8], dv[9];
    #pragma unroll
    for (int k = 0; k < 9; k++) cw[k] = pp[k];
    #pragma unroll
    for (int k = 0; k < 9; k++) chv[k] = pp[9 + k];
    #pragma unroll
    for (int k = 0; k < 8; k++) wd[k] = pp[18 + k];
    #pragma unroll
    for (int k = 0; k < 8; k++) hg[k] = pp[26 + k];
    #pragma unroll
    for (int k = 0; k < 9; k++) dv[k] = pp[34 + k];

    const int tid = threadIdx.x;
    size_t base0 = (size_t)bc * LLEN + (size_t)blockIdx.x * 2048 + (size_t)tid * 4;
    size_t base1 = base0 + 1024;
    float4 ya = *reinterpret_cast<const float4*>(xin + base0);
    float4 yb = *reinterpret_cast<const float4*>(xin + base1);

    float ldsum = 0.f;
    float4 oa, ob;
    rqs_elem(cw, chv, wd, hg, dv, ya.x, oa.x, ldsum);
    rqs_elem(cw, chv, wd, hg, dv, ya.y, oa.y, ldsum);
    rqs_elem(cw, chv, wd, hg, dv, ya.z, oa.z, ldsum);
    rqs_elem(cw, chv, wd, hg, dv, ya.w, oa.w, ldsum);
    rqs_elem(cw, chv, wd, hg, dv, yb.x, ob.x, ldsum);
    rqs_elem(cw, chv, wd, hg, dv, yb.y, ob.y, ldsum);
    rqs_elem(cw, chv, wd, hg, dv, yb.z, ob.z, ldsum);
    rqs_elem(cw, chv, wd, hg, dv, yb.w, ob.w, ldsum);
    *reinterpret_cast<float4*>(xout + base0) = oa;
    *reinterpret_cast<float4*>(xout + base1) = ob;

    #pragma unroll
    for (int off = 32; off > 0; off >>= 1) ldsum += __shfl_xor(ldsum, off, 64);
    __shared__ float red[4];
    if ((tid & 63) == 0) red[tid >> 6] = ldsum;
    __syncthreads();
    if (tid == 0) {
        float sb = red[0] + red[1] + red[2] + red[3];
        atomicAdd(&logdet[bc >> 3], sb * (1.0f / (float)LLEN));
    }
}

// ---------------------------------------------------------------- launch
extern "C" void kernel_launch(void* const* d_in, const int* in_sizes, int n_in,
                              void* d_out, int out_size, void* d_ws, size_t ws_size,
                              hipStream_t stream) {
    const float* cin   = (const float*)d_in[1];
    const float* noise = (const float*)d_in[2];
    const float* w0    = (const float*)d_in[3];
    const float* b0    = (const float*)d_in[4];
    const float* wh    = (const float*)d_in[5];
    const float* bh    = (const float*)d_in[6];
    const float* w_out = (const float*)d_in[7];
    const float* b_out = (const float*)d_in[8];

    float* xout   = (float*)d_out;                       // [128*8*8192]
    float* logdet = xout + (size_t)BATCH * CX * LLEN;    // [128]

    float* ws     = (float*)d_ws;
    float* hbar0  = ws;                                  // 4096 floats
    float* hbar1  = ws + 4096;                           // 4096 floats
    float* params = ws + 8192;                           // 1024*48 floats
    unsigned short* wf = (unsigned short*)(ws + 8192 + 1024 * PSTR);  // 24576 ushorts

    zero_kernel<<<32, 256, 0, stream>>>(ws, logdet);     // hbar0|hbar1 + logdet
    repack_frag_kernel<<<96, 256, 0, stream>>>(w0, wh, wf);

    for (int t = 0; t < NSTEP; t++) {
        const float* xcur = (t == 0) ? noise : xout;
        float* hbar = (t == 0) ? hbar0 : hbar1;
        conv_kernel<<<dim3(LLEN / TILE, BATCH), NT, 0, stream>>>(
            cin, xcur,
            wf + t * 12288, b0 + t * HID, bh + t * 3 * HID,
            hbar);
        params_kernel<<<(BATCH * CX + 255) / 256, 256, 0, stream>>>(
            hbar, w_out + t * POUT * HID, b_out + t * POUT, params);
        rqs_kernel<<<dim3(LLEN / 2048, BATCH * CX), 256, 0, stream>>>(
            params, xcur, xout, logdet);
    }
}

// Round 5
// 257.257 us; speedup vs baseline: 5.6031x; 1.4278x over previous
//
#include <hip/hip_runtime.h>
#include <hip/hip_bf16.h>

// Sizes (fixed by the problem)
#define BATCH 128
#define CCOND 16          // conditioning channels
#define CX    8           // flow channels
#define CIN0  24          // CCOND + CX
#define HID   32
#define LLEN  8192
#define NSTEP 2
#define PDIM  23          // 3K-1, K=8
#define POUT  184         // PDIM * CX
#define PSTR  48          // per-(b,c) param record stride in ws

// conv tiling: one wave = one independent 32-output window, no block barriers
#define WPW   32          // final outputs per wave
#define SROWS 40          // staged rows per wave: g in [gb-4, gb+36)
#define RSTR  40          // bf16 stride per row (80 B)
#define LWORDS (SROWS * RSTR)   // 1600 bf16 per buffer

typedef __bf16 bf16x8 __attribute__((ext_vector_type(8)));
typedef __bf16 bf16x4 __attribute__((ext_vector_type(4)));
typedef float  f32x4  __attribute__((ext_vector_type(4)));

// wave-local LDS visibility fence (no cross-wave sync needed)
#define WAVE_SYNC() do { \
    asm volatile("s_waitcnt lgkmcnt(0)" ::: "memory"); \
    __builtin_amdgcn_sched_barrier(0); \
} while (0)

__device__ __forceinline__ unsigned short f2bf(float f) {
    unsigned u = __float_as_uint(f);
    return (unsigned short)((u + 0x7FFFu + ((u >> 16) & 1u)) >> 16);
}

// ---------------------------------------------------------------- util
// zeros hbar0|hbar1 (ws[0..8192)) and logdet[0..128)
__global__ void zero_kernel(float* __restrict__ ws, float* __restrict__ logdet) {
    int i = blockIdx.x * 256 + threadIdx.x;
    ws[i] = 0.f;
    if (i < BATCH) logdet[i] = 0.f;
}

// Pack conv weights into exact per-lane MFMA A-fragment order (bf16).
// wf[t][layer][s][mt][lane][j]; element = W[co = mt*16+(lane&15)]
//                                          [ci = (lane>>4)*8+j][koff = s]
__global__ void repack_frag_kernel(const float* __restrict__ w0,   // [2][32][24][3]
                                   const float* __restrict__ wh,   // [2][3][32][32][3]
                                   unsigned short* __restrict__ wf) {
    int i = blockIdx.x * 256 + threadIdx.x;     // 24576 total
    int j = i & 7, lane = (i >> 3) & 63, q = i >> 9;
    int mt = q & 1; q >>= 1;
    int s = q % 3;  q /= 3;
    int l = q & 3, t = q >> 2;
    int m = mt * 16 + (lane & 15);
    int ci = (lane >> 4) * 8 + j;
    float v;
    if (l == 0)
        v = (ci < CIN0) ? w0[((t * HID + m) * CIN0 + ci) * 3 + s] : 0.f;
    else
        v = wh[(((t * 3 + (l - 1)) * HID + m) * HID + ci) * 3 + s];
    wf[i] = f2bf(v);
}

// ---------------------------------------------------------------- fused convs
// One layer over the wave's private window: bin rows [o-1,o+1] -> bout row o,
// for o = starts[t] + prow (overlapping tiles recompute rows idempotently).
// Rows whose global g is outside [0,L) are forced to 0 (SAME zero padding).
template<int NTL, int LAST>
__device__ __forceinline__ void wconv_layer(
        const __bf16* __restrict__ bin, __bf16* __restrict__ bout,
        const unsigned short* __restrict__ wl, const float* __restrict__ bp,
        const int* starts, int gb, int lane, float* __restrict__ vs) {
    const int prow = lane & 15, grp = lane >> 4;
    const int ci0 = grp * 8, co0 = grp * 4;

    bf16x8 af[3][2];
    #pragma unroll
    for (int s = 0; s < 3; ++s)
        #pragma unroll
        for (int mt = 0; mt < 2; ++mt)
            af[s][mt] = *reinterpret_cast<const bf16x8*>(
                wl + ((s * 2 + mt) << 9) + (lane << 3));
    f32x4 bias0 = *reinterpret_cast<const f32x4*>(bp + co0);
    f32x4 bias1 = *reinterpret_cast<const f32x4*>(bp + 16 + co0);

    #pragma unroll
    for (int t = 0; t < NTL; ++t) {
        const int o = starts[t] + prow;
        bf16x8 bf0 = *reinterpret_cast<const bf16x8*>(&bin[(o - 1) * RSTR + ci0]);
        bf16x8 bf1 = *reinterpret_cast<const bf16x8*>(&bin[(o    ) * RSTR + ci0]);
        bf16x8 bf2 = *reinterpret_cast<const bf16x8*>(&bin[(o + 1) * RSTR + ci0]);
        f32x4 a0 = bias0, a1 = bias1;
        a0 = __builtin_amdgcn_mfma_f32_16x16x32_bf16(af[0][0], bf0, a0, 0, 0, 0);
        a1 = __builtin_amdgcn_mfma_f32_16x16x32_bf16(af[0][1], bf0, a1, 0, 0, 0);
        a0 = __builtin_amdgcn_mfma_f32_16x16x32_bf16(af[1][0], bf1, a0, 0, 0, 0);
        a1 = __builtin_amdgcn_mfma_f32_16x16x32_bf16(af[1][1], bf1, a1, 0, 0, 0);
        a0 = __builtin_amdgcn_mfma_f32_16x16x32_bf16(af[2][0], bf2, a0, 0, 0, 0);
        a1 = __builtin_amdgcn_mfma_f32_16x16x32_bf16(af[2][1], bf2, a1, 0, 0, 0);
        const bool ok = (unsigned)(gb - 4 + o) < (unsigned)LLEN;
        #pragma unroll
        for (int r = 0; r < 4; ++r) {
            a0[r] = ok ? fmaxf(a0[r], 0.f) : 0.f;
            a1[r] = ok ? fmaxf(a1[r], 0.f) : 0.f;
        }
        if (!LAST) {
            bf16x4 p0, p1;
            #pragma unroll
            for (int r = 0; r < 4; ++r) { p0[r] = (__bf16)a0[r]; p1[r] = (__bf16)a1[r]; }
            *reinterpret_cast<bf16x4*>(&bout[o * RSTR + co0]) = p0;
            *reinterpret_cast<bf16x4*>(&bout[o * RSTR + 16 + co0]) = p1;
        } else {
            #pragma unroll
            for (int r = 0; r < 4; ++r) { vs[r] += a0[r]; vs[4 + r] += a1[r]; }
        }
    }
}

__global__ __launch_bounds__(256, 6) void conv_kernel(
        const float* __restrict__ cin,   // [B][16][L]
        const float* __restrict__ xin,   // [B][8][L]
        const unsigned short* __restrict__ wf,  // this t: [4][3][2][64][8]
        const float* __restrict__ b0p,   // [32]   (this t)
        const float* __restrict__ bhp,   // [3][32](this t)
        float* __restrict__ hbar) {      // [B][32] sums (atomic)
    __shared__ __align__(16) __bf16 lds[4][2][LWORDS];
    __shared__ float psum[4][HID];

    const int tid = threadIdx.x;
    const int lane = tid & 63, wv = tid >> 6;
    const int b = blockIdx.y;
    const int gb = blockIdx.x * (4 * WPW) + wv * WPW;
    const int sub = lane & 3;
    const int prow = lane & 15, grp = lane >> 4;

    __bf16* bufA = &lds[wv][0][0];
    __bf16* bufB = &lds[wv][1][0];

    // ---- stage: coalesced float4 loads, 4x4 lane transpose, b64 LDS writes
    #pragma unroll
    for (int rnd = 0; rnd < 4; ++rnd) {
        int g4 = rnd * 16 + (lane >> 2);        // group: 4 lanes = 4 ch x 4 pos
        if (g4 < 60) {
            int cb = g4 / 10, qq = g4 - cb * 10;
            int ch = cb * 4 + sub;
            int g = gb - 4 + qq * 4;
            float4 f = make_float4(0.f, 0.f, 0.f, 0.f);
            if ((unsigned)g < (unsigned)LLEN) {
                const float* src = (ch < CCOND)
                    ? cin + ((size_t)b * CCOND + ch) * LLEN
                    : xin + ((size_t)b * CX + (ch - CCOND)) * LLEN;
                f = *reinterpret_cast<const float4*>(src + g);
            }
            // transpose within the 4-lane group: lane ends with 4 ch @ 1 pos
            float tv0 = 0.f, tv1 = 0.f, tv2 = 0.f, tv3 = 0.f;
            #pragma unroll
            for (int r = 0; r < 4; ++r) {
                int ksel = (sub - r) & 3;
                float x = ksel == 0 ? f.x : ksel == 1 ? f.y : ksel == 2 ? f.z : f.w;
                int j = (sub + r) & 3;
                float v = __shfl(x, (lane & ~3) | j, 64);
                tv0 = (j == 0) ? v : tv0;
                tv1 = (j == 1) ? v : tv1;
                tv2 = (j == 2) ? v : tv2;
                tv3 = (j == 3) ? v : tv3;
            }
            int p = qq * 4 + sub;
            bf16x4 pk;
            pk[0] = (__bf16)tv0; pk[1] = (__bf16)tv1;
            pk[2] = (__bf16)tv2; pk[3] = (__bf16)tv3;
            *reinterpret_cast<bf16x4*>(&bufA[p * RSTR + cb * 4]) = pk;
        }
    }
    // zero K-padding channels 24..31
    if (lane < SROWS)
        *reinterpret_cast<uint4*>(&bufA[lane * RSTR + 24]) = make_uint4(0, 0, 0, 0);
    WAVE_SYNC();

    float vs[8] = {0.f, 0.f, 0.f, 0.f, 0.f, 0.f, 0.f, 0.f};
    const int s0[3] = {1, 17, 23};
    const int s1[3] = {2, 18, 22};
    const int s2[3] = {3, 19, 21};
    const int s3[2] = {4, 20};
    wconv_layer<3, 0>(bufA, bufB, wf,        b0p,      s0, gb, lane, vs);
    WAVE_SYNC();
    wconv_layer<3, 0>(bufB, bufA, wf + 3072, bhp,      s1, gb, lane, vs);
    WAVE_SYNC();
    wconv_layer<3, 0>(bufA, bufB, wf + 6144, bhp + 32, s2, gb, lane, vs);
    WAVE_SYNC();
    wconv_layer<2, 1>(bufB, bufA, wf + 9216, bhp + 64, s3, gb, lane, vs);

    // reduce vs over the 16 position-lanes (co fixed within each xor group)
    #pragma unroll
    for (int off = 1; off < 16; off <<= 1)
        #pragma unroll
        for (int r = 0; r < 8; ++r)
            vs[r] += __shfl_xor(vs[r], off, 64);
    const int co0 = grp * 4;
    if (prow == 0) {
        #pragma unroll
        for (int r = 0; r < 4; ++r) {
            psum[wv][co0 + r] = vs[r];
            psum[wv][16 + co0 + r] = vs[4 + r];
        }
    }
    __syncthreads();
    if (tid < HID) {
        float s = psum[0][tid] + psum[1][tid] + psum[2][tid] + psum[3][tid];
        atomicAdd(&hbar[b * HID + tid], s);
    }
}

// ---------------------------------------------------------------- spline prep
__device__ __forceinline__ float softplusf(float v) {
    return fmaxf(v, 0.f) + log1pf(expf(-fabsf(v)));
}

// One thread per (b,c): p = w_out * mean(h) + b_out, then knot arrays.
// Record layout (stride PSTR): cw[0..8], ch[9..17], w[18..25], h[26..33], d[34..42]
__global__ void params_kernel(const float* __restrict__ hbar,   // [B][32] sums
                              const float* __restrict__ w_out,  // [184][32] for this t
                              const float* __restrict__ b_out,  // [184]
                              float* __restrict__ params) {
    int tg = blockIdx.x * 256 + threadIdx.x;
    if (tg >= BATCH * CX) return;
    int b = tg >> 3, c = tg & 7;
    const float invL = 1.0f / (float)LLEN;

    float hb[HID];
    #pragma unroll
    for (int h = 0; h < HID; h++) hb[h] = hbar[b * HID + h] * invL;

    float p[PDIM];
    #pragma unroll
    for (int j = 0; j < PDIM; j++) {
        int cp = c * PDIM + j;
        float acc = b_out[cp];
        #pragma unroll
        for (int h = 0; h < HID; h++) acc = fmaf(w_out[cp * HID + h], hb[h], acc);
        p[j] = acc;
    }

    float* out = params + (size_t)tg * PSTR;

    // widths -> knot x positions
    {
        float mx = p[0];
        #pragma unroll
        for (int k = 1; k < 8; k++) mx = fmaxf(mx, p[k]);
        float e[8], se = 0.f;
        #pragma unroll
        for (int k = 0; k < 8; k++) { e[k] = expf(p[k] - mx); se += e[k]; }
        float inv = 1.f / se, cum = 0.f;
        float cw[9]; cw[0] = -3.f;
        #pragma unroll
        for (int k = 0; k < 8; k++) {
            float wk = 1e-3f + (1.f - 8e-3f) * (e[k] * inv);
            cum += wk;
            cw[k + 1] = 6.f * cum - 3.f;
        }
        #pragma unroll
        for (int k = 0; k < 9; k++) out[k] = cw[k];
        #pragma unroll
        for (int k = 0; k < 8; k++) out[18 + k] = cw[k + 1] - cw[k];
    }
    // heights -> knot y positions
    {
        float mx = p[8];
        #pragma unroll
        for (int k = 1; k < 8; k++) mx = fmaxf(mx, p[8 + k]);
        float e[8], se = 0.f;
        #pragma unroll
        for (int k = 0; k < 8; k++) { e[k] = expf(p[8 + k] - mx); se += e[k]; }
        float inv = 1.f / se, cum = 0.f;
        float ch[9]; ch[0] = -3.f;
        #pragma unroll
        for (int k = 0; k < 8; k++) {
            float hk = 1e-3f + (1.f - 8e-3f) * (e[k] * inv);
            cum += hk;
            ch[k + 1] = 6.f * cum - 3.f;
        }
        #pragma unroll
        for (int k = 0; k < 9; k++) out[9 + k] = ch[k];
        #pragma unroll
        for (int k = 0; k < 8; k++) out[26 + k] = ch[k + 1] - ch[k];
    }
    // derivatives (boundary = 1)
    out[34] = 1.f;
    #pragma unroll
    for (int k = 0; k < 7; k++) out[35 + k] = 1e-3f + softplusf(p[16 + k]);
    out[42] = 1.f;
}

// ---------------------------------------------------------------- RQS inverse
// 8 elements/thread (2x float4, hoisted loads). Params wave-uniform -> SGPRs;
// bin gather = branchless cndmask tree; raw v_log/v_sqrt/v_rcp.
__device__ __forceinline__ void rqs_elem(
        const float* cw, const float* chv, const float* wd,
        const float* hg, const float* dv,
        float y, float& ov, float& ldsum) {
    bool inside = fabsf(y) <= 3.0f;
    float yc = fminf(fmaxf(y, -3.f), 3.f);

    float icw = cw[0], iw = wd[0], ich = chv[0], ih = hg[0];
    float dk = dv[0], dk1 = dv[1];
    #pragma unroll
    for (int k = 1; k < 8; k++) {
        bool c = yc >= chv[k];
        icw = c ? cw[k]  : icw;
        iw  = c ? wd[k]  : iw;
        ich = c ? chv[k] : ich;
        ih  = c ? hg[k]  : ih;
        dk  = c ? dv[k]  : dk;
        dk1 = c ? dv[k + 1] : dk1;
    }
    float s  = ih * __builtin_amdgcn_rcpf(iw);
    float dy = yc - ich;
    float t1 = dk + dk1 - 2.f * s;
    float a  = ih * (s - dk) + dy * t1;
    float bq = ih * dk - dy * t1;
    float cq = -s * dy;
    float disc = fmaxf(bq * bq - 4.f * a * cq, 0.f);
    float den  = -bq - __builtin_amdgcn_sqrtf(disc);
    float root = (2.f * cq) * __builtin_amdgcn_rcpf(den);
    float om = 1.f - root;
    float outv  = fmaf(root, iw, icw);
    float denom = fmaf(t1 * root, om, s);
    float dnum  = s * s * (dk1 * root * root + 2.f * s * root * om + dk * om * om);
    float ld = (2.f * __builtin_amdgcn_logf(denom) - __builtin_amdgcn_logf(dnum))
               * 0.69314718055994531f;
    ov = inside ? outv : y;
    ldsum += inside ? ld : 0.f;
}

__global__ __launch_bounds__(256) void rqs_kernel(const float* __restrict__ params,
                                                  const float* __restrict__ xin,
                                                  float* __restrict__ xout,
                                                  float* __restrict__ logdet) {
    const int bc = blockIdx.y;
    const float* __restrict__ pp = params + (size_t)bc * PSTR;
    float cw[9], chv[9], wd[8], hg[8], dv[9];
    #pragma unroll
    for (int k = 0; k < 9; k++) cw[k] = pp[k];
    #pragma unroll
    for (int k = 0; k < 9; k++) chv[k] = pp[9 + k];
    #pragma unroll
    for (int k = 0; k < 8; k++) wd[k] = pp[18 + k];
    #pragma unroll
    for (int k = 0; k < 8; k++) hg[k] = pp[26 + k];
    #pragma unroll
    for (int k = 0; k < 9; k++) dv[k] = pp[34 + k];

    const int tid = threadIdx.x;
    size_t base0 = (size_t)bc * LLEN + (size_t)blockIdx.x * 2048 + (size_t)tid * 4;
    size_t base1 = base0 + 1024;
    float4 ya = *reinterpret_cast<const float4*>(xin + base0);
    float4 yb = *reinterpret_cast<const float4*>(xin + base1);

    float ldsum = 0.f;
    float4 oa, ob;
    rqs_elem(cw, chv, wd, hg, dv, ya.x, oa.x, ldsum);
    rqs_elem(cw, chv, wd, hg, dv, ya.y, oa.y, ldsum);
    rqs_elem(cw, chv, wd, hg, dv, ya.z, oa.z, ldsum);
    rqs_elem(cw, chv, wd, hg, dv, ya.w, oa.w, ldsum);
    rqs_elem(cw, chv, wd, hg, dv, yb.x, ob.x, ldsum);
    rqs_elem(cw, chv, wd, hg, dv, yb.y, ob.y, ldsum);
    rqs_elem(cw, chv, wd, hg, dv, yb.z, ob.z, ldsum);
    rqs_elem(cw, chv, wd, hg, dv, yb.w, ob.w, ldsum);
    *reinterpret_cast<float4*>(xout + base0) = oa;
    *reinterpret_cast<float4*>(xout + base1) = ob;

    #pragma unroll
    for (int off = 32; off > 0; off >>= 1) ldsum += __shfl_xor(ldsum, off, 64);
    __shared__ float red[4];
    if ((tid & 63) == 0) red[tid >> 6] = ldsum;
    __syncthreads();
    if (tid == 0) {
        float sb = red[0] + red[1] + red[2] + red[3];
        atomicAdd(&logdet[bc >> 3], sb * (1.0f / (float)LLEN));
    }
}

// ---------------------------------------------------------------- launch
extern "C" void kernel_launch(void* const* d_in, const int* in_sizes, int n_in,
                              void* d_out, int out_size, void* d_ws, size_t ws_size,
                              hipStream_t stream) {
    const float* cin   = (const float*)d_in[1];
    const float* noise = (const float*)d_in[2];
    const float* w0    = (const float*)d_in[3];
    const float* b0    = (const float*)d_in[4];
    const float* wh    = (const float*)d_in[5];
    const float* bh    = (const float*)d_in[6];
    const float* w_out = (const float*)d_in[7];
    const float* b_out = (const float*)d_in[8];

    float* xout   = (float*)d_out;                       // [128*8*8192]
    float* logdet = xout + (size_t)BATCH * CX * LLEN;    // [128]

    float* ws     = (float*)d_ws;
    float* hbar0  = ws;                                  // 4096 floats
    float* hbar1  = ws + 4096;                           // 4096 floats
    float* params = ws + 8192;                           // 1024*48 floats
    unsigned short* wf = (unsigned short*)(ws + 8192 + 1024 * PSTR);  // 24576 ushorts

    zero_kernel<<<32, 256, 0, stream>>>(ws, logdet);     // hbar0|hbar1 + logdet
    repack_frag_kernel<<<96, 256, 0, stream>>>(w0, wh, wf);

    for (int t = 0; t < NSTEP; t++) {
        const float* xcur = (t == 0) ? noise : xout;
        float* hbar = (t == 0) ? hbar0 : hbar1;
        conv_kernel<<<dim3(LLEN / (4 * WPW), BATCH), 256, 0, stream>>>(
            cin, xcur,
            wf + t * 12288, b0 + t * HID, bh + t * 3 * HID,
            hbar);
        params_kernel<<<(BATCH * CX + 255) / 256, 256, 0, stream>>>(
            hbar, w_out + t * POUT * HID, b_out + t * POUT, params);
        rqs_kernel<<<dim3(LLEN / 2048, BATCH * CX), 256, 0, stream>>>(
            params, xcur, xout, logdet);
    }
}

// Round 6
// 221.940 us; speedup vs baseline: 6.4947x; 1.1591x over previous
//
#include <hip/hip_runtime.h>
#include <hip/hip_bf16.h>

// Sizes (fixed by the problem)
#define BATCH 128
#define CCOND 16          // conditioning channels
#define CX    8           // flow channels
#define CIN0  24          // CCOND + CX
#define HID   32
#define LLEN  8192
#define NSTEP 2
#define PDIM  23          // 3K-1, K=8
#define POUT  184         // PDIM * CX
#define PSTR  48          // per-(b,c) param record stride in ws

// conv tiling: one wave = one independent 32-output window, no block barriers
#define WPW   32          // final outputs per wave
#define SROWS 40          // staged rows per wave: g in [gb-4, gb+36)
#define RSTR  40          // bf16 stride per row (80 B)
#define LWORDS (SROWS * RSTR)   // 1600 bf16 per buffer

typedef __bf16 bf16x8 __attribute__((ext_vector_type(8)));
typedef __bf16 bf16x4 __attribute__((ext_vector_type(4)));
typedef float  f32x4  __attribute__((ext_vector_type(4)));

// wave-local LDS ordering fence: drain DS queue so layer-l writes complete
// before layer-l+1 reads issue (DS pipe is in-order per wave; this is cheap).
#define WAVE_SYNC() asm volatile("s_waitcnt lgkmcnt(0)" ::: "memory")

// DPP lane-move (VALU pipe — replaces ds_bpermute shuffles)
template<int CTRL>
__device__ __forceinline__ float dpp_movf(float v) {
    return __int_as_float(
        __builtin_amdgcn_mov_dpp(__float_as_int(v), CTRL, 0xF, 0xF, true));
}
// quad_perm rotate-by-r encodings
#define QROT1 0x39
#define QROT2 0x4E
#define QROT3 0x93
// row_ror:N (16-lane row rotations)
#define RROR1 0x121
#define RROR2 0x122
#define RROR4 0x124
#define RROR8 0x128

__device__ __forceinline__ unsigned short f2bf(float f) {
    unsigned u = __float_as_uint(f);
    return (unsigned short)((u + 0x7FFFu + ((u >> 16) & 1u)) >> 16);
}

// ---------------------------------------------------------------- util
// zeros hbar0|hbar1 (ws[0..8192)) and logdet[0..128)
__global__ void zero_kernel(float* __restrict__ ws, float* __restrict__ logdet) {
    int i = blockIdx.x * 256 + threadIdx.x;
    ws[i] = 0.f;
    if (i < BATCH) logdet[i] = 0.f;
}

// Pack conv weights into exact per-lane MFMA A-fragment order (bf16).
// wf[t][layer][s][mt][lane][j]; element = W[co = mt*16+(lane&15)]
//                                          [ci = (lane>>4)*8+j][koff = s]
__global__ void repack_frag_kernel(const float* __restrict__ w0,   // [2][32][24][3]
                                   const float* __restrict__ wh,   // [2][3][32][32][3]
                                   unsigned short* __restrict__ wf) {
    int i = blockIdx.x * 256 + threadIdx.x;     // 24576 total
    int j = i & 7, lane = (i >> 3) & 63, q = i >> 9;
    int mt = q & 1; q >>= 1;
    int s = q % 3;  q /= 3;
    int l = q & 3, t = q >> 2;
    int m = mt * 16 + (lane & 15);
    int ci = (lane >> 4) * 8 + j;
    float v;
    if (l == 0)
        v = (ci < CIN0) ? w0[((t * HID + m) * CIN0 + ci) * 3 + s] : 0.f;
    else
        v = wh[(((t * 3 + (l - 1)) * HID + m) * HID + ci) * 3 + s];
    wf[i] = f2bf(v);
}

// ---------------------------------------------------------------- fused convs
// One layer over the wave's private window: bin rows [o-1,o+1] -> bout row o,
// for o = starts[t] + prow (overlapping tiles recompute rows idempotently).
// Rows whose global g is outside [0,L) are forced to 0 (SAME zero padding).
// All fragment reads are issued up-front so they stream on the DS pipe.
template<int NTL, int LAST>
__device__ __forceinline__ void wconv_layer(
        const __bf16* __restrict__ bin, __bf16* __restrict__ bout,
        const unsigned short* __restrict__ wl, const float* __restrict__ bp,
        const int (&starts)[NTL], int gb, int lane, float* __restrict__ vs) {
    const int prow = lane & 15, grp = lane >> 4;
    const int ci0 = grp * 8, co0 = grp * 4;

    bf16x8 af[3][2];
    #pragma unroll
    for (int s = 0; s < 3; ++s)
        #pragma unroll
        for (int mt = 0; mt < 2; ++mt)
            af[s][mt] = *reinterpret_cast<const bf16x8*>(
                wl + ((s * 2 + mt) << 9) + (lane << 3));
    f32x4 bias0 = *reinterpret_cast<const f32x4*>(bp + co0);
    f32x4 bias1 = *reinterpret_cast<const f32x4*>(bp + 16 + co0);

    bf16x8 bfr[NTL][3];
    #pragma unroll
    for (int t = 0; t < NTL; ++t) {
        const int o = starts[t] + prow;
        #pragma unroll
        for (int tap = 0; tap < 3; ++tap)
            bfr[t][tap] = *reinterpret_cast<const bf16x8*>(
                &bin[(o + tap - 1) * RSTR + ci0]);
    }

    #pragma unroll
    for (int t = 0; t < NTL; ++t) {
        const int o = starts[t] + prow;
        f32x4 a0 = bias0, a1 = bias1;
        a0 = __builtin_amdgcn_mfma_f32_16x16x32_bf16(af[0][0], bfr[t][0], a0, 0, 0, 0);
        a1 = __builtin_amdgcn_mfma_f32_16x16x32_bf16(af[0][1], bfr[t][0], a1, 0, 0, 0);
        a0 = __builtin_amdgcn_mfma_f32_16x16x32_bf16(af[1][0], bfr[t][1], a0, 0, 0, 0);
        a1 = __builtin_amdgcn_mfma_f32_16x16x32_bf16(af[1][1], bfr[t][1], a1, 0, 0, 0);
        a0 = __builtin_amdgcn_mfma_f32_16x16x32_bf16(af[2][0], bfr[t][2], a0, 0, 0, 0);
        a1 = __builtin_amdgcn_mfma_f32_16x16x32_bf16(af[2][1], bfr[t][2], a1, 0, 0, 0);
        const bool ok = (unsigned)(gb - 4 + o) < (unsigned)LLEN;
        #pragma unroll
        for (int r = 0; r < 4; ++r) {
            a0[r] = ok ? fmaxf(a0[r], 0.f) : 0.f;
            a1[r] = ok ? fmaxf(a1[r], 0.f) : 0.f;
        }
        if (!LAST) {
            bf16x4 p0, p1;
            #pragma unroll
            for (int r = 0; r < 4; ++r) { p0[r] = (__bf16)a0[r]; p1[r] = (__bf16)a1[r]; }
            *reinterpret_cast<bf16x4*>(&bout[o * RSTR + co0]) = p0;
            *reinterpret_cast<bf16x4*>(&bout[o * RSTR + 16 + co0]) = p1;
        } else {
            #pragma unroll
            for (int r = 0; r < 4; ++r) { vs[r] += a0[r]; vs[4 + r] += a1[r]; }
        }
    }
}

__global__ __launch_bounds__(256, 6) void conv_kernel(
        const float* __restrict__ cin,   // [B][16][L]
        const float* __restrict__ xin,   // [B][8][L]
        const unsigned short* __restrict__ wf,  // this t: [4][3][2][64][8]
        const float* __restrict__ b0p,   // [32]   (this t)
        const float* __restrict__ bhp,   // [3][32](this t)
        float* __restrict__ hbar) {      // [B][32] sums (atomic)
    __shared__ __align__(16) __bf16 lds[4][2][LWORDS];
    __shared__ float psum[4][HID];

    const int tid = threadIdx.x;
    const int lane = tid & 63, wv = tid >> 6;
    const int b = blockIdx.y;
    const int gb = blockIdx.x * (4 * WPW) + wv * WPW;
    const int sub = lane & 3;
    const int prow = lane & 15, grp = lane >> 4;

    __bf16* bufA = &lds[wv][0][0];
    __bf16* bufB = &lds[wv][1][0];

    // ---- stage: coalesced float4 loads, 4x4 DPP quad transpose, b64 writes
    #pragma unroll
    for (int rnd = 0; rnd < 4; ++rnd) {
        int g4 = rnd * 16 + (lane >> 2);        // group: 4 lanes = 4 ch x 4 pos
        if (g4 < 60) {
            int cb = g4 / 10, qq = g4 - cb * 10;
            int ch = cb * 4 + sub;
            int g = gb - 4 + qq * 4;
            float4 f = make_float4(0.f, 0.f, 0.f, 0.f);
            if ((unsigned)g < (unsigned)LLEN) {
                const float* src = (ch < CCOND)
                    ? cin + ((size_t)b * CCOND + ch) * LLEN
                    : xin + ((size_t)b * CX + (ch - CCOND)) * LLEN;
                f = *reinterpret_cast<const float4*>(src + g);
            }
            // transpose within the 4-lane quad via DPP: lane ends with
            // 4 channels @ 1 position (pos = qq*4 + sub)
            float tv0 = 0.f, tv1 = 0.f, tv2 = 0.f, tv3 = 0.f;
            {   // r = 0: value stays on-lane, goes to tv[sub]
                float x = sub == 0 ? f.x : sub == 1 ? f.y : sub == 2 ? f.z : f.w;
                tv0 = (sub == 0) ? x : tv0;
                tv1 = (sub == 1) ? x : tv1;
                tv2 = (sub == 2) ? x : tv2;
                tv3 = (sub == 3) ? x : tv3;
            }
            {   // r = 1
                int ks = (sub - 1) & 3;
                float x = ks == 0 ? f.x : ks == 1 ? f.y : ks == 2 ? f.z : f.w;
                float v = dpp_movf<QROT1>(x);
                int j = (sub + 1) & 3;
                tv0 = (j == 0) ? v : tv0;
                tv1 = (j == 1) ? v : tv1;
                tv2 = (j == 2) ? v : tv2;
                tv3 = (j == 3) ? v : tv3;
            }
            {   // r = 2
                int ks = (sub - 2) & 3;
                float x = ks == 0 ? f.x : ks == 1 ? f.y : ks == 2 ? f.z : f.w;
                float v = dpp_movf<QROT2>(x);
                int j = (sub + 2) & 3;
                tv0 = (j == 0) ? v : tv0;
                tv1 = (j == 1) ? v : tv1;
                tv2 = (j == 2) ? v : tv2;
                tv3 = (j == 3) ? v : tv3;
            }
            {   // r = 3
                int ks = (sub - 3) & 3;
                float x = ks == 0 ? f.x : ks == 1 ? f.y : ks == 2 ? f.z : f.w;
                float v = dpp_movf<QROT3>(x);
                int j = (sub + 3) & 3;
                tv0 = (j == 0) ? v : tv0;
                tv1 = (j == 1) ? v : tv1;
                tv2 = (j == 2) ? v : tv2;
                tv3 = (j == 3) ? v : tv3;
            }
            int p = qq * 4 + sub;
            bf16x4 pk;
            pk[0] = (__bf16)tv0; pk[1] = (__bf16)tv1;
            pk[2] = (__bf16)tv2; pk[3] = (__bf16)tv3;
            *reinterpret_cast<bf16x4*>(&bufA[p * RSTR + cb * 4]) = pk;
        }
    }
    // zero K-padding channels 24..31
    if (lane < SROWS)
        *reinterpret_cast<uint4*>(&bufA[lane * RSTR + 24]) = make_uint4(0, 0, 0, 0);
    WAVE_SYNC();

    float vs[8] = {0.f, 0.f, 0.f, 0.f, 0.f, 0.f, 0.f, 0.f};
    const int s0[3] = {1, 17, 23};
    const int s1[3] = {2, 18, 22};
    const int s2[3] = {3, 19, 21};
    const int s3[2] = {4, 20};
    wconv_layer<3, 0>(bufA, bufB, wf,        b0p,      s0, gb, lane, vs);
    WAVE_SYNC();
    wconv_layer<3, 0>(bufB, bufA, wf + 3072, bhp,      s1, gb, lane, vs);
    WAVE_SYNC();
    wconv_layer<3, 0>(bufA, bufB, wf + 6144, bhp + 32, s2, gb, lane, vs);
    WAVE_SYNC();
    wconv_layer<2, 1>(bufB, bufA, wf + 9216, bhp + 64, s3, gb, lane, vs);

    // reduce vs over the 16 position-lanes via DPP row rotations (VALU pipe)
    #pragma unroll
    for (int r = 0; r < 8; ++r) {
        vs[r] += dpp_movf<RROR8>(vs[r]);
        vs[r] += dpp_movf<RROR4>(vs[r]);
        vs[r] += dpp_movf<RROR2>(vs[r]);
        vs[r] += dpp_movf<RROR1>(vs[r]);
    }
    const int co0 = grp * 4;
    if (prow == 0) {
        #pragma unroll
        for (int r = 0; r < 4; ++r) {
            psum[wv][co0 + r] = vs[r];
            psum[wv][16 + co0 + r] = vs[4 + r];
        }
    }
    __syncthreads();
    if (tid < HID) {
        float s = psum[0][tid] + psum[1][tid] + psum[2][tid] + psum[3][tid];
        atomicAdd(&hbar[b * HID + tid], s);
    }
}

// ---------------------------------------------------------------- spline prep
__device__ __forceinline__ float softplusf(float v) {
    return fmaxf(v, 0.f) + log1pf(expf(-fabsf(v)));
}

// One thread per (b,c): p = w_out * mean(h) + b_out, then knot arrays.
// w_out and this block's hbar slice staged in LDS (padded, conflict-free).
// Record layout (stride PSTR): cw[0..8], ch[9..17], w[18..25], h[26..33], d[34..42]
__global__ __launch_bounds__(256) void params_kernel(
        const float* __restrict__ hbar,   // [B][32] sums
        const float* __restrict__ w_out,  // [184][32] for this t
        const float* __restrict__ b_out,  // [184]
        float* __restrict__ params) {
    __shared__ float wsh[POUT][HID + 1];
    __shared__ float hsh[32][HID];
    const int tid = threadIdx.x;
    const float invL = 1.0f / (float)LLEN;
    for (int i = tid; i < POUT * HID; i += 256)
        wsh[i >> 5][i & 31] = w_out[i];
    for (int i = tid; i < 32 * HID; i += 256)
        hsh[i >> 5][i & 31] = hbar[blockIdx.x * 32 * HID + i] * invL;
    __syncthreads();

    int tg = blockIdx.x * 256 + tid;
    int bl = tid >> 3, c = tid & 7;

    float p[PDIM];
    #pragma unroll
    for (int j = 0; j < PDIM; j++) {
        int cp = c * PDIM + j;
        float acc = b_out[cp];
        #pragma unroll
        for (int h = 0; h < HID; h++) acc = fmaf(wsh[cp][h], hsh[bl][h], acc);
        p[j] = acc;
    }

    float* out = params + (size_t)tg * PSTR;

    // widths -> knot x positions
    {
        float mx = p[0];
        #pragma unroll
        for (int k = 1; k < 8; k++) mx = fmaxf(mx, p[k]);
        float e[8], se = 0.f;
        #pragma unroll
        for (int k = 0; k < 8; k++) { e[k] = expf(p[k] - mx); se += e[k]; }
        float inv = 1.f / se, cum = 0.f;
        float cw[9]; cw[0] = -3.f;
        #pragma unroll
        for (int k = 0; k < 8; k++) {
            float wk = 1e-3f + (1.f - 8e-3f) * (e[k] * inv);
            cum += wk;
            cw[k + 1] = 6.f * cum - 3.f;
        }
        #pragma unroll
        for (int k = 0; k < 9; k++) out[k] = cw[k];
        #pragma unroll
        for (int k = 0; k < 8; k++) out[18 + k] = cw[k + 1] - cw[k];
    }
    // heights -> knot y positions
    {
        float mx = p[8];
        #pragma unroll
        for (int k = 1; k < 8; k++) mx = fmaxf(mx, p[8 + k]);
        float e[8], se = 0.f;
        #pragma unroll
        for (int k = 0; k < 8; k++) { e[k] = expf(p[8 + k] - mx); se += e[k]; }
        float inv = 1.f / se, cum = 0.f;
        float ch[9]; ch[0] = -3.f;
        #pragma unroll
        for (int k = 0; k < 8; k++) {
            float hk = 1e-3f + (1.f - 8e-3f) * (e[k] * inv);
            cum += hk;
            ch[k + 1] = 6.f * cum - 3.f;
        }
        #pragma unroll
        for (int k = 0; k < 9; k++) out[9 + k] = ch[k];
        #pragma unroll
        for (int k = 0; k < 8; k++) out[26 + k] = ch[k + 1] - ch[k];
    }
    // derivatives (boundary = 1)
    out[34] = 1.f;
    #pragma unroll
    for (int k = 0; k < 7; k++) out[35 + k] = 1e-3f + softplusf(p[16 + k]);
    out[42] = 1.f;
}

// ---------------------------------------------------------------- RQS inverse
// 8 elements/thread (2x float4, hoisted loads). Params wave-uniform -> SGPRs;
// bin gather = branchless cndmask tree; raw v_log/v_sqrt/v_rcp.
__device__ __forceinline__ void rqs_elem(
        const float* cw, const float* chv, const float* wd,
        const float* hg, const float* dv,
        float y, float& ov, float& ldsum) {
    bool inside = fabsf(y) <= 3.0f;
    float yc = fminf(fmaxf(y, -3.f), 3.f);

    float icw = cw[0], iw = wd[0], ich = chv[0], ih = hg[0];
    float dk = dv[0], dk1 = dv[1];
    #pragma unroll
    for (int k = 1; k < 8; k++) {
        bool c = yc >= chv[k];
        icw = c ? cw[k]  : icw;
        iw  = c ? wd[k]  : iw;
        ich = c ? chv[k] : ich;
        ih  = c ? hg[k]  : ih;
        dk  = c ? dv[k]  : dk;
        dk1 = c ? dv[k + 1] : dk1;
    }
    float s  = ih * __builtin_amdgcn_rcpf(iw);
    float dy = yc - ich;
    float t1 = dk + dk1 - 2.f * s;
    float a  = ih * (s - dk) + dy * t1;
    float bq = ih * dk - dy * t1;
    float cq = -s * dy;
    float disc = fmaxf(bq * bq - 4.f * a * cq, 0.f);
    float den  = -bq - __builtin_amdgcn_sqrtf(disc);
    float root = (2.f * cq) * __builtin_amdgcn_rcpf(den);
    float om = 1.f - root;
    float outv  = fmaf(root, iw, icw);
    float denom = fmaf(t1 * root, om, s);
    float dnum  = s * s * (dk1 * root * root + 2.f * s * root * om + dk * om * om);
    float ld = (2.f * __builtin_amdgcn_logf(denom) - __builtin_amdgcn_logf(dnum))
               * 0.69314718055994531f;
    ov = inside ? outv : y;
    ldsum += inside ? ld : 0.f;
}

__global__ __launch_bounds__(256) void rqs_kernel(const float* __restrict__ params,
                                                  const float* __restrict__ xin,
                                                  float* __restrict__ xout,
                                                  float* __restrict__ logdet) {
    const int bc = blockIdx.y;
    const float* __restrict__ pp = params + (size_t)bc * PSTR;
    float cw[9], chv[9], wd[8], hg[8], dv[9];
    #pragma unroll
    for (int k = 0; k < 9; k++) cw[k] = pp[k];
    #pragma unroll
    for (int k = 0; k < 9; k++) chv[k] = pp[9 + k];
    #pragma unroll
    for (int k = 0; k < 8; k++) wd[k] = pp[18 + k];
    #pragma unroll
    for (int k = 0; k < 8; k++) hg[k] = pp[26 + k];
    #pragma unroll
    for (int k = 0; k < 9; k++) dv[k] = pp[34 + k];

    const int tid = threadIdx.x;
    size_t base0 = (size_t)bc * LLEN + (size_t)blockIdx.x * 2048 + (size_t)tid * 4;
    size_t base1 = base0 + 1024;
    float4 ya = *reinterpret_cast<const float4*>(xin + base0);
    float4 yb = *reinterpret_cast<const float4*>(xin + base1);

    float ldsum = 0.f;
    float4 oa, ob;
    rqs_elem(cw, chv, wd, hg, dv, ya.x, oa.x, ldsum);
    rqs_elem(cw, chv, wd, hg, dv, ya.y, oa.y, ldsum);
    rqs_elem(cw, chv, wd, hg, dv, ya.z, oa.z, ldsum);
    rqs_elem(cw, chv, wd, hg, dv, ya.w, oa.w, ldsum);
    rqs_elem(cw, chv, wd, hg, dv, yb.x, ob.x, ldsum);
    rqs_elem(cw, chv, wd, hg, dv, yb.y, ob.y, ldsum);
    rqs_elem(cw, chv, wd, hg, dv, yb.z, ob.z, ldsum);
    rqs_elem(cw, chv, wd, hg, dv, yb.w, ob.w, ldsum);
    *reinterpret_cast<float4*>(xout + base0) = oa;
    *reinterpret_cast<float4*>(xout + base1) = ob;

    #pragma unroll
    for (int off = 32; off > 0; off >>= 1) ldsum += __shfl_xor(ldsum, off, 64);
    __shared__ float red[4];
    if ((tid & 63) == 0) red[tid >> 6] = ldsum;
    __syncthreads();
    if (tid == 0) {
        float sb = red[0] + red[1] + red[2] + red[3];
        atomicAdd(&logdet[bc >> 3], sb * (1.0f / (float)LLEN));
    }
}

// ---------------------------------------------------------------- launch
extern "C" void kernel_launch(void* const* d_in, const int* in_sizes, int n_in,
                              void* d_out, int out_size, void* d_ws, size_t ws_size,
                              hipStream_t stream) {
    const float* cin   = (const float*)d_in[1];
    const float* noise = (const float*)d_in[2];
    const float* w0    = (const float*)d_in[3];
    const float* b0    = (const float*)d_in[4];
    const float* wh    = (const float*)d_in[5];
    const float* bh    = (const float*)d_in[6];
    const float* w_out = (const float*)d_in[7];
    const float* b_out = (const float*)d_in[8];

    float* xout   = (float*)d_out;                       // [128*8*8192]
    float* logdet = xout + (size_t)BATCH * CX * LLEN;    // [128]

    float* ws     = (float*)d_ws;
    float* hbar0  = ws;                                  // 4096 floats
    float* hbar1  = ws + 4096;                           // 4096 floats
    float* params = ws + 8192;                           // 1024*48 floats
    unsigned short* wf = (unsigned short*)(ws + 8192 + 1024 * PSTR);  // 24576 ushorts

    zero_kernel<<<32, 256, 0, stream>>>(ws, logdet);     // hbar0|hbar1 + logdet
    repack_frag_kernel<<<96, 256, 0, stream>>>(w0, wh, wf);

    for (int t = 0; t < NSTEP; t++) {
        const float* xcur = (t == 0) ? noise : xout;
        float* hbar = (t == 0) ? hbar0 : hbar1;
        conv_kernel<<<dim3(LLEN / (4 * WPW), BATCH), 256, 0, stream>>>(
            cin, xcur,
            wf + t * 12288, b0 + t * HID, bh + t * 3 * HID,
            hbar);
        params_kernel<<<BATCH * CX / 256, 256, 0, stream>>>(
            hbar, w_out + t * POUT * HID, b_out + t * POUT, params);
        rqs_kernel<<<dim3(LLEN / 2048, BATCH * CX), 256, 0, stream>>>(
            params, xcur, xout, logdet);
    }
}

// Round 7
// 207.976 us; speedup vs baseline: 6.9308x; 1.0671x over previous
//
#include <hip/hip_runtime.h>
#include <hip/hip_bf16.h>

// Sizes (fixed by the problem)
#define BATCH 128
#define CCOND 16          // conditioning channels
#define CX    8           // flow channels
#define CIN0  24          // CCOND + CX
#define HID   32
#define LLEN  8192
#define NSTEP 2
#define PDIM  23          // 3K-1, K=8
#define POUT  184         // PDIM * CX
#define PSTR  48          // per-(b,c) param record stride in ws

// conv tiling: one wave = one independent 32-output window, no block barriers
#define WPW   32          // final outputs per wave
#define SROWS 40          // staged rows per wave: g in [gb-4, gb+36)
#define RSTR  40          // bf16 stride per row (80 B)
#define LWORDS (SROWS * RSTR)   // 1600 bf16 per buffer

typedef __bf16 bf16x8 __attribute__((ext_vector_type(8)));
typedef __bf16 bf16x4 __attribute__((ext_vector_type(4)));
typedef float  f32x4  __attribute__((ext_vector_type(4)));

// wave-local LDS ordering fence: drain DS queue so layer-l writes complete
// before layer-l+1 reads issue (DS pipe is in-order per wave; this is cheap).
#define WAVE_SYNC() asm volatile("s_waitcnt lgkmcnt(0)" ::: "memory")

// DPP lane-move (VALU pipe — replaces ds_bpermute shuffles)
template<int CTRL>
__device__ __forceinline__ float dpp_movf(float v) {
    return __int_as_float(
        __builtin_amdgcn_mov_dpp(__float_as_int(v), CTRL, 0xF, 0xF, true));
}
// quad_perm rotate-by-r encodings
#define QROT1 0x39
#define QROT2 0x4E
#define QROT3 0x93
// row_ror:N (16-lane row rotations)
#define RROR1 0x121
#define RROR2 0x122
#define RROR4 0x124
#define RROR8 0x128

__device__ __forceinline__ unsigned short f2bf(float f) {
    unsigned u = __float_as_uint(f);
    return (unsigned short)((u + 0x7FFFu + ((u >> 16) & 1u)) >> 16);
}

// ---------------------------------------------------------------- util
// zeros hbar0|hbar1 (ws[0..8192)) and logdet[0..128)
__global__ void zero_kernel(float* __restrict__ ws, float* __restrict__ logdet) {
    int i = blockIdx.x * 256 + threadIdx.x;
    ws[i] = 0.f;
    if (i < BATCH) logdet[i] = 0.f;
}

// Pack conv weights into exact per-lane MFMA A-fragment order (bf16).
// wf[t][layer][s][mt][lane][j]; element = W[co = mt*16+(lane&15)]
//                                          [ci = (lane>>4)*8+j][koff = s]
__global__ void repack_frag_kernel(const float* __restrict__ w0,   // [2][32][24][3]
                                   const float* __restrict__ wh,   // [2][3][32][32][3]
                                   unsigned short* __restrict__ wf) {
    int i = blockIdx.x * 256 + threadIdx.x;     // 24576 total
    int j = i & 7, lane = (i >> 3) & 63, q = i >> 9;
    int mt = q & 1; q >>= 1;
    int s = q % 3;  q /= 3;
    int l = q & 3, t = q >> 2;
    int m = mt * 16 + (lane & 15);
    int ci = (lane >> 4) * 8 + j;
    float v;
    if (l == 0)
        v = (ci < CIN0) ? w0[((t * HID + m) * CIN0 + ci) * 3 + s] : 0.f;
    else
        v = wh[(((t * 3 + (l - 1)) * HID + m) * HID + ci) * 3 + s];
    wf[i] = f2bf(v);
}

// ---------------------------------------------------------------- fused convs
// One layer over the wave's private window: bin rows [o-1,o+1] -> bout row o,
// for o = starts[t] + prow (overlapping tiles recompute rows idempotently).
// Rows whose global g is outside [0,L) are forced to 0 (SAME zero padding).
// All fragment reads are issued up-front (sched_barrier keeps them there).
template<int NTL, int LAST>
__device__ __forceinline__ void wconv_layer(
        const __bf16* __restrict__ bin, __bf16* __restrict__ bout,
        const unsigned short* __restrict__ wl, const float* __restrict__ bp,
        const int (&starts)[NTL], int gb, int lane, float* __restrict__ vs) {
    const int prow = lane & 15, grp = lane >> 4;
    const int ci0 = grp * 8, co0 = grp * 4;

    bf16x8 af[3][2];
    #pragma unroll
    for (int s = 0; s < 3; ++s)
        #pragma unroll
        for (int mt = 0; mt < 2; ++mt)
            af[s][mt] = *reinterpret_cast<const bf16x8*>(
                wl + ((s * 2 + mt) << 9) + (lane << 3));
    f32x4 bias0 = *reinterpret_cast<const f32x4*>(bp + co0);
    f32x4 bias1 = *reinterpret_cast<const f32x4*>(bp + 16 + co0);

    // issue ALL fragment reads first; barrier pins them ahead of the MFMAs
    bf16x8 bfr[NTL][3];
    #pragma unroll
    for (int t = 0; t < NTL; ++t) {
        const int o = starts[t] + prow;
        #pragma unroll
        for (int tap = 0; tap < 3; ++tap)
            bfr[t][tap] = *reinterpret_cast<const bf16x8*>(
                &bin[(o + tap - 1) * RSTR + ci0]);
    }
    __builtin_amdgcn_sched_barrier(0);

    #pragma unroll
    for (int t = 0; t < NTL; ++t) {
        const int o = starts[t] + prow;
        f32x4 a0 = bias0, a1 = bias1;
        a0 = __builtin_amdgcn_mfma_f32_16x16x32_bf16(af[0][0], bfr[t][0], a0, 0, 0, 0);
        a1 = __builtin_amdgcn_mfma_f32_16x16x32_bf16(af[0][1], bfr[t][0], a1, 0, 0, 0);
        a0 = __builtin_amdgcn_mfma_f32_16x16x32_bf16(af[1][0], bfr[t][1], a0, 0, 0, 0);
        a1 = __builtin_amdgcn_mfma_f32_16x16x32_bf16(af[1][1], bfr[t][1], a1, 0, 0, 0);
        a0 = __builtin_amdgcn_mfma_f32_16x16x32_bf16(af[2][0], bfr[t][2], a0, 0, 0, 0);
        a1 = __builtin_amdgcn_mfma_f32_16x16x32_bf16(af[2][1], bfr[t][2], a1, 0, 0, 0);
        const bool ok = (unsigned)(gb - 4 + o) < (unsigned)LLEN;
        #pragma unroll
        for (int r = 0; r < 4; ++r) {
            a0[r] = ok ? fmaxf(a0[r], 0.f) : 0.f;
            a1[r] = ok ? fmaxf(a1[r], 0.f) : 0.f;
        }
        if (!LAST) {
            bf16x4 p0, p1;
            #pragma unroll
            for (int r = 0; r < 4; ++r) { p0[r] = (__bf16)a0[r]; p1[r] = (__bf16)a1[r]; }
            *reinterpret_cast<bf16x4*>(&bout[o * RSTR + co0]) = p0;
            *reinterpret_cast<bf16x4*>(&bout[o * RSTR + 16 + co0]) = p1;
        } else {
            #pragma unroll
            for (int r = 0; r < 4; ++r) { vs[r] += a0[r]; vs[4 + r] += a1[r]; }
        }
    }
}

__global__ __launch_bounds__(256, 4) void conv_kernel(
        const float* __restrict__ cin,   // [B][16][L]
        const float* __restrict__ xin,   // [B][8][L]
        const unsigned short* __restrict__ wf,  // this t: [4][3][2][64][8]
        const float* __restrict__ b0p,   // [32]   (this t)
        const float* __restrict__ bhp,   // [3][32](this t)
        float* __restrict__ hbar) {      // [B][32] sums (atomic)
    __shared__ __align__(16) __bf16 lds[4][2][LWORDS];
    __shared__ float psum[4][HID];

    const int tid = threadIdx.x;
    const int lane = tid & 63, wv = tid >> 6;
    const int b = blockIdx.y;
    const int gb = blockIdx.x * (4 * WPW) + wv * WPW;
    const int sub = lane & 3;
    const int prow = lane & 15, grp = lane >> 4;

    __bf16* bufA = &lds[wv][0][0];
    __bf16* bufB = &lds[wv][1][0];

    // ---- stage: issue all 4 coalesced float4 loads first, then transpose
    float4 fv[4];
    #pragma unroll
    for (int rnd = 0; rnd < 4; ++rnd) {
        int g4 = rnd * 16 + (lane >> 2);        // group: 4 lanes = 4 ch x 4 pos
        fv[rnd] = make_float4(0.f, 0.f, 0.f, 0.f);
        if (g4 < 60) {
            int cb = g4 / 10, qq = g4 - cb * 10;
            int ch = cb * 4 + sub;
            int g = gb - 4 + qq * 4;
            if ((unsigned)g < (unsigned)LLEN) {
                const float* src = (ch < CCOND)
                    ? cin + ((size_t)b * CCOND + ch) * LLEN
                    : xin + ((size_t)b * CX + (ch - CCOND)) * LLEN;
                fv[rnd] = *reinterpret_cast<const float4*>(src + g);
            }
        }
    }
    __builtin_amdgcn_sched_barrier(0);
    #pragma unroll
    for (int rnd = 0; rnd < 4; ++rnd) {
        int g4 = rnd * 16 + (lane >> 2);
        if (g4 < 60) {
            int cb = g4 / 10, qq = g4 - cb * 10;
            float4 f = fv[rnd];
            // transpose within the 4-lane quad via DPP: lane ends with
            // 4 channels @ 1 position (pos = qq*4 + sub)
            float tv0 = 0.f, tv1 = 0.f, tv2 = 0.f, tv3 = 0.f;
            {   // r = 0: value stays on-lane, goes to tv[sub]
                float x = sub == 0 ? f.x : sub == 1 ? f.y : sub == 2 ? f.z : f.w;
                tv0 = (sub == 0) ? x : tv0;
                tv1 = (sub == 1) ? x : tv1;
                tv2 = (sub == 2) ? x : tv2;
                tv3 = (sub == 3) ? x : tv3;
            }
            {   // r = 1
                int ks = (sub - 1) & 3;
                float x = ks == 0 ? f.x : ks == 1 ? f.y : ks == 2 ? f.z : f.w;
                float v = dpp_movf<QROT1>(x);
                int j = (sub + 1) & 3;
                tv0 = (j == 0) ? v : tv0;
                tv1 = (j == 1) ? v : tv1;
                tv2 = (j == 2) ? v : tv2;
                tv3 = (j == 3) ? v : tv3;
            }
            {   // r = 2
                int ks = (sub - 2) & 3;
                float x = ks == 0 ? f.x : ks == 1 ? f.y : ks == 2 ? f.z : f.w;
                float v = dpp_movf<QROT2>(x);
                int j = (sub + 2) & 3;
                tv0 = (j == 0) ? v : tv0;
                tv1 = (j == 1) ? v : tv1;
                tv2 = (j == 2) ? v : tv2;
                tv3 = (j == 3) ? v : tv3;
            }
            {   // r = 3
                int ks = (sub - 3) & 3;
                float x = ks == 0 ? f.x : ks == 1 ? f.y : ks == 2 ? f.z : f.w;
                float v = dpp_movf<QROT3>(x);
                int j = (sub + 3) & 3;
                tv0 = (j == 0) ? v : tv0;
                tv1 = (j == 1) ? v : tv1;
                tv2 = (j == 2) ? v : tv2;
                tv3 = (j == 3) ? v : tv3;
            }
            int p = qq * 4 + sub;
            bf16x4 pk;
            pk[0] = (__bf16)tv0; pk[1] = (__bf16)tv1;
            pk[2] = (__bf16)tv2; pk[3] = (__bf16)tv3;
            *reinterpret_cast<bf16x4*>(&bufA[p * RSTR + cb * 4]) = pk;
        }
    }
    // zero K-padding channels 24..31
    if (lane < SROWS)
        *reinterpret_cast<uint4*>(&bufA[lane * RSTR + 24]) = make_uint4(0, 0, 0, 0);
    WAVE_SYNC();

    float vs[8] = {0.f, 0.f, 0.f, 0.f, 0.f, 0.f, 0.f, 0.f};
    const int s0[3] = {1, 17, 23};
    const int s1[3] = {2, 18, 22};
    const int s2[3] = {3, 19, 21};
    const int s3[2] = {4, 20};
    wconv_layer<3, 0>(bufA, bufB, wf,        b0p,      s0, gb, lane, vs);
    WAVE_SYNC();
    wconv_layer<3, 0>(bufB, bufA, wf + 3072, bhp,      s1, gb, lane, vs);
    WAVE_SYNC();
    wconv_layer<3, 0>(bufA, bufB, wf + 6144, bhp + 32, s2, gb, lane, vs);
    WAVE_SYNC();
    wconv_layer<2, 1>(bufB, bufA, wf + 9216, bhp + 64, s3, gb, lane, vs);

    // reduce vs over the 16 position-lanes via DPP row rotations (VALU pipe)
    #pragma unroll
    for (int r = 0; r < 8; ++r) {
        vs[r] += dpp_movf<RROR8>(vs[r]);
        vs[r] += dpp_movf<RROR4>(vs[r]);
        vs[r] += dpp_movf<RROR2>(vs[r]);
        vs[r] += dpp_movf<RROR1>(vs[r]);
    }
    const int co0 = grp * 4;
    if (prow == 0) {
        #pragma unroll
        for (int r = 0; r < 4; ++r) {
            psum[wv][co0 + r] = vs[r];
            psum[wv][16 + co0 + r] = vs[4 + r];
        }
    }
    __syncthreads();
    if (tid < HID) {
        float s = psum[0][tid] + psum[1][tid] + psum[2][tid] + psum[3][tid];
        atomicAdd(&hbar[b * HID + tid], s);
    }
}

// ---------------------------------------------------------------- spline prep
__device__ __forceinline__ float softplusf(float v) {
    return fmaxf(v, 0.f) + log1pf(expf(-fabsf(v)));
}

// One thread per (b,c): p = w_out * mean(h) + b_out, then knot arrays.
// w_out and this block's hbar slice staged in LDS (padded, conflict-free).
// Record layout (stride PSTR): cw[0..8], ch[9..17], w[18..25], h[26..33], d[34..42]
__global__ __launch_bounds__(256) void params_kernel(
        const float* __restrict__ hbar,   // [B][32] sums
        const float* __restrict__ w_out,  // [184][32] for this t
        const float* __restrict__ b_out,  // [184]
        float* __restrict__ params) {
    __shared__ float wsh[POUT][HID + 1];
    __shared__ float hsh[32][HID];
    const int tid = threadIdx.x;
    const float invL = 1.0f / (float)LLEN;
    for (int i = tid; i < POUT * HID; i += 256)
        wsh[i >> 5][i & 31] = w_out[i];
    for (int i = tid; i < 32 * HID; i += 256)
        hsh[i >> 5][i & 31] = hbar[blockIdx.x * 32 * HID + i] * invL;
    __syncthreads();

    int tg = blockIdx.x * 256 + tid;
    int bl = tid >> 3, c = tid & 7;

    float p[PDIM];
    #pragma unroll
    for (int j = 0; j < PDIM; j++) {
        int cp = c * PDIM + j;
        float acc = b_out[cp];
        #pragma unroll
        for (int h = 0; h < HID; h++) acc = fmaf(wsh[cp][h], hsh[bl][h], acc);
        p[j] = acc;
    }

    float* out = params + (size_t)tg * PSTR;

    // widths -> knot x positions
    {
        float mx = p[0];
        #pragma unroll
        for (int k = 1; k < 8; k++) mx = fmaxf(mx, p[k]);
        float e[8], se = 0.f;
        #pragma unroll
        for (int k = 0; k < 8; k++) { e[k] = expf(p[k] - mx); se += e[k]; }
        float inv = 1.f / se, cum = 0.f;
        float cw[9]; cw[0] = -3.f;
        #pragma unroll
        for (int k = 0; k < 8; k++) {
            float wk = 1e-3f + (1.f - 8e-3f) * (e[k] * inv);
            cum += wk;
            cw[k + 1] = 6.f * cum - 3.f;
        }
        #pragma unroll
        for (int k = 0; k < 9; k++) out[k] = cw[k];
        #pragma unroll
        for (int k = 0; k < 8; k++) out[18 + k] = cw[k + 1] - cw[k];
    }
    // heights -> knot y positions
    {
        float mx = p[8];
        #pragma unroll
        for (int k = 1; k < 8; k++) mx = fmaxf(mx, p[8 + k]);
        float e[8], se = 0.f;
        #pragma unroll
        for (int k = 0; k < 8; k++) { e[k] = expf(p[8 + k] - mx); se += e[k]; }
        float inv = 1.f / se, cum = 0.f;
        float ch[9]; ch[0] = -3.f;
        #pragma unroll
        for (int k = 0; k < 8; k++) {
            float hk = 1e-3f + (1.f - 8e-3f) * (e[k] * inv);
            cum += hk;
            ch[k + 1] = 6.f * cum - 3.f;
        }
        #pragma unroll
        for (int k = 0; k < 9; k++) out[9 + k] = ch[k];
        #pragma unroll
        for (int k = 0; k < 8; k++) out[26 + k] = ch[k + 1] - ch[k];
    }
    // derivatives (boundary = 1)
    out[34] = 1.f;
    #pragma unroll
    for (int k = 0; k < 7; k++) out[35 + k] = 1e-3f + softplusf(p[16 + k]);
    out[42] = 1.f;
}

// ---------------------------------------------------------------- RQS inverse
// 8 elements/thread (2x float4, hoisted loads). Params wave-uniform -> SGPRs;
// bin gather = branchless cndmask tree; raw v_log/v_sqrt/v_rcp.
__device__ __forceinline__ void rqs_elem(
        const float* cw, const float* chv, const float* wd,
        const float* hg, const float* dv,
        float y, float& ov, float& ldsum) {
    bool inside = fabsf(y) <= 3.0f;
    float yc = fminf(fmaxf(y, -3.f), 3.f);

    float icw = cw[0], iw = wd[0], ich = chv[0], ih = hg[0];
    float dk = dv[0], dk1 = dv[1];
    #pragma unroll
    for (int k = 1; k < 8; k++) {
        bool c = yc >= chv[k];
        icw = c ? cw[k]  : icw;
        iw  = c ? wd[k]  : iw;
        ich = c ? chv[k] : ich;
        ih  = c ? hg[k]  : ih;
        dk  = c ? dv[k]  : dk;
        dk1 = c ? dv[k + 1] : dk1;
    }
    float s  = ih * __builtin_amdgcn_rcpf(iw);
    float dy = yc - ich;
    float t1 = dk + dk1 - 2.f * s;
    float a  = ih * (s - dk) + dy * t1;
    float bq = ih * dk - dy * t1;
    float cq = -s * dy;
    float disc = fmaxf(bq * bq - 4.f * a * cq, 0.f);
    float den  = -bq - __builtin_amdgcn_sqrtf(disc);
    float root = (2.f * cq) * __builtin_amdgcn_rcpf(den);
    float om = 1.f - root;
    float outv  = fmaf(root, iw, icw);
    float denom = fmaf(t1 * root, om, s);
    float dnum  = s * s * (dk1 * root * root + 2.f * s * root * om + dk * om * om);
    float ld = (2.f * __builtin_amdgcn_logf(denom) - __builtin_amdgcn_logf(dnum))
               * 0.69314718055994531f;
    ov = inside ? outv : y;
    ldsum += inside ? ld : 0.f;
}

__global__ __launch_bounds__(256) void rqs_kernel(const float* __restrict__ params,
                                                  const float* __restrict__ xin,
                                                  float* __restrict__ xout,
                                                  float* __restrict__ logdet) {
    const int bc = blockIdx.y;
    const float* __restrict__ pp = params + (size_t)bc * PSTR;
    float cw[9], chv[9], wd[8], hg[8], dv[9];
    #pragma unroll
    for (int k = 0; k < 9; k++) cw[k] = pp[k];
    #pragma unroll
    for (int k = 0; k < 9; k++) chv[k] = pp[9 + k];
    #pragma unroll
    for (int k = 0; k < 8; k++) wd[k] = pp[18 + k];
    #pragma unroll
    for (int k = 0; k < 8; k++) hg[k] = pp[26 + k];
    #pragma unroll
    for (int k = 0; k < 9; k++) dv[k] = pp[34 + k];

    const int tid = threadIdx.x;
    size_t base0 = (size_t)bc * LLEN + (size_t)blockIdx.x * 2048 + (size_t)tid * 4;
    size_t base1 = base0 + 1024;
    float4 ya = *reinterpret_cast<const float4*>(xin + base0);
    float4 yb = *reinterpret_cast<const float4*>(xin + base1);

    float ldsum = 0.f;
    float4 oa, ob;
    rqs_elem(cw, chv, wd, hg, dv, ya.x, oa.x, ldsum);
    rqs_elem(cw, chv, wd, hg, dv, ya.y, oa.y, ldsum);
    rqs_elem(cw, chv, wd, hg, dv, ya.z, oa.z, ldsum);
    rqs_elem(cw, chv, wd, hg, dv, ya.w, oa.w, ldsum);
    rqs_elem(cw, chv, wd, hg, dv, yb.x, ob.x, ldsum);
    rqs_elem(cw, chv, wd, hg, dv, yb.y, ob.y, ldsum);
    rqs_elem(cw, chv, wd, hg, dv, yb.z, ob.z, ldsum);
    rqs_elem(cw, chv, wd, hg, dv, yb.w, ob.w, ldsum);
    *reinterpret_cast<float4*>(xout + base0) = oa;
    *reinterpret_cast<float4*>(xout + base1) = ob;

    #pragma unroll
    for (int off = 32; off > 0; off >>= 1) ldsum += __shfl_xor(ldsum, off, 64);
    __shared__ float red[4];
    if ((tid & 63) == 0) red[tid >> 6] = ldsum;
    __syncthreads();
    if (tid == 0) {
        float sb = red[0] + red[1] + red[2] + red[3];
        atomicAdd(&logdet[bc >> 3], sb * (1.0f / (float)LLEN));
    }
}

// ---------------------------------------------------------------- launch
extern "C" void kernel_launch(void* const* d_in, const int* in_sizes, int n_in,
                              void* d_out, int out_size, void* d_ws, size_t ws_size,
                              hipStream_t stream) {
    const float* cin   = (const float*)d_in[1];
    const float* noise = (const float*)d_in[2];
    const float* w0    = (const float*)d_in[3];
    const float* b0    = (const float*)d_in[4];
    const float* wh    = (const float*)d_in[5];
    const float* bh    = (const float*)d_in[6];
    const float* w_out = (const float*)d_in[7];
    const float* b_out = (const float*)d_in[8];

    float* xout   = (float*)d_out;                       // [128*8*8192]
    float* logdet = xout + (size_t)BATCH * CX * LLEN;    // [128]

    float* ws     = (float*)d_ws;
    float* hbar0  = ws;                                  // 4096 floats
    float* hbar1  = ws + 4096;                           // 4096 floats
    float* params = ws + 8192;                           // 1024*48 floats
    unsigned short* wf = (unsigned short*)(ws + 8192 + 1024 * PSTR);  // 24576 ushorts

    zero_kernel<<<32, 256, 0, stream>>>(ws, logdet);     // hbar0|hbar1 + logdet
    repack_frag_kernel<<<96, 256, 0, stream>>>(w0, wh, wf);

    for (int t = 0; t < NSTEP; t++) {
        const float* xcur = (t == 0) ? noise : xout;
        float* hbar = (t == 0) ? hbar0 : hbar1;
        conv_kernel<<<dim3(LLEN / (4 * WPW), BATCH), 256, 0, stream>>>(
            cin, xcur,
            wf + t * 12288, b0 + t * HID, bh + t * 3 * HID,
            hbar);
        params_kernel<<<BATCH * CX / 256, 256, 0, stream>>>(
            hbar, w_out + t * POUT * HID, b_out + t * POUT, params);
        rqs_kernel<<<dim3(LLEN / 2048, BATCH * CX), 256, 0, stream>>>(
            params, xcur, xout, logdet);
    }
}

// Round 8
// 186.737 us; speedup vs baseline: 7.7190x; 1.1137x over previous
//
#include <hip/hip_runtime.h>
#include <hip/hip_bf16.h>

// Sizes (fixed by the problem)
#define BATCH 128
#define CCOND 16          // conditioning channels
#define CX    8           // flow channels
#define CIN0  24          // CCOND + CX
#define HID   32
#define LLEN  8192
#define NSTEP 2
#define PDIM  23          // 3K-1, K=8
#define POUT  184         // PDIM * CX
#define PSTR  48          // per-(b,c) param record stride in ws

// conv tiling: one wave = one independent 48-output window, no block barriers
#define WPW   48          // final outputs per wave
#define SROWS 56          // staged rows per wave: g in [gb-4, gb+52)
#define RSTR  40          // bf16 stride per row (80 B, 16B-aligned, 2-way banks)
#define LWORDS (SROWS * RSTR)   // 2240 bf16 per buffer
#define GRIDX 43          // ceil(8192 / 192)

typedef __bf16 bf16x8 __attribute__((ext_vector_type(8)));
typedef __bf16 bf16x4 __attribute__((ext_vector_type(4)));
typedef float  f32x4  __attribute__((ext_vector_type(4)));

// wave-local LDS ordering fence (DS pipe is in-order per wave)
#define WAVE_SYNC() asm volatile("s_waitcnt lgkmcnt(0)" ::: "memory")

// DPP lane-move (VALU pipe) for the 16-lane reduce
template<int CTRL>
__device__ __forceinline__ float dpp_movf(float v) {
    return __int_as_float(
        __builtin_amdgcn_mov_dpp(__float_as_int(v), CTRL, 0xF, 0xF, true));
}
#define RROR1 0x121
#define RROR2 0x122
#define RROR4 0x124
#define RROR8 0x128

__device__ __forceinline__ unsigned short f2bf(float f) {
    unsigned u = __float_as_uint(f);
    return (unsigned short)((u + 0x7FFFu + ((u >> 16) & 1u)) >> 16);
}

// ---------------------------------------------------------------- util
// zeros hbar0|hbar1 (ws[0..8192)) and logdet[0..128)
__global__ void zero_kernel(float* __restrict__ ws, float* __restrict__ logdet) {
    int i = blockIdx.x * 256 + threadIdx.x;
    ws[i] = 0.f;
    if (i < BATCH) logdet[i] = 0.f;
}

// Pack conv weights into exact per-lane MFMA A-fragment order (bf16).
// wf[t][layer][s][mt][lane][j]; element = W[co = mt*16+(lane&15)]
//                                          [ci = (lane>>4)*8+j][koff = s]
__global__ void repack_frag_kernel(const float* __restrict__ w0,   // [2][32][24][3]
                                   const float* __restrict__ wh,   // [2][3][32][32][3]
                                   unsigned short* __restrict__ wf) {
    int i = blockIdx.x * 256 + threadIdx.x;     // 24576 total
    int j = i & 7, lane = (i >> 3) & 63, q = i >> 9;
    int mt = q & 1; q >>= 1;
    int s = q % 3;  q /= 3;
    int l = q & 3, t = q >> 2;
    int m = mt * 16 + (lane & 15);
    int ci = (lane >> 4) * 8 + j;
    float v;
    if (l == 0)
        v = (ci < CIN0) ? w0[((t * HID + m) * CIN0 + ci) * 3 + s] : 0.f;
    else
        v = wh[(((t * 3 + (l - 1)) * HID + m) * HID + ci) * 3 + s];
    wf[i] = f2bf(v);
}

// ---------------------------------------------------------------- fused convs
// One layer over the wave's private window: bin rows [o-1,o+1] -> bout row o,
// o = starts[t] + prow (overlapping tiles recompute rows idempotently).
// Rows whose global g is outside [0,L) are forced to 0 (SAME zero padding).
template<int NTL, int LAST>
__device__ __forceinline__ void wconv_layer(
        const __bf16* __restrict__ bin, __bf16* __restrict__ bout,
        const unsigned short* __restrict__ wl, const float* __restrict__ bp,
        const int (&starts)[NTL], int gb, int lane, float* __restrict__ vs) {
    const int prow = lane & 15, grp = lane >> 4;
    const int ci0 = grp * 8, co0 = grp * 4;

    bf16x8 af[3][2];
    #pragma unroll
    for (int s = 0; s < 3; ++s)
        #pragma unroll
        for (int mt = 0; mt < 2; ++mt)
            af[s][mt] = *reinterpret_cast<const bf16x8*>(
                wl + ((s * 2 + mt) << 9) + (lane << 3));
    f32x4 bias0 = *reinterpret_cast<const f32x4*>(bp + co0);
    f32x4 bias1 = *reinterpret_cast<const f32x4*>(bp + 16 + co0);

    // issue ALL fragment reads first; barrier pins them ahead of the MFMAs
    bf16x8 bfr[NTL][3];
    #pragma unroll
    for (int t = 0; t < NTL; ++t) {
        const int o = starts[t] + prow;
        #pragma unroll
        for (int tap = 0; tap < 3; ++tap)
            bfr[t][tap] = *reinterpret_cast<const bf16x8*>(
                &bin[(o + tap - 1) * RSTR + ci0]);
    }
    __builtin_amdgcn_sched_barrier(0);

    #pragma unroll
    for (int t = 0; t < NTL; ++t) {
        const int o = starts[t] + prow;
        f32x4 a0 = bias0, a1 = bias1;
        a0 = __builtin_amdgcn_mfma_f32_16x16x32_bf16(af[0][0], bfr[t][0], a0, 0, 0, 0);
        a1 = __builtin_amdgcn_mfma_f32_16x16x32_bf16(af[0][1], bfr[t][0], a1, 0, 0, 0);
        a0 = __builtin_amdgcn_mfma_f32_16x16x32_bf16(af[1][0], bfr[t][1], a0, 0, 0, 0);
        a1 = __builtin_amdgcn_mfma_f32_16x16x32_bf16(af[1][1], bfr[t][1], a1, 0, 0, 0);
        a0 = __builtin_amdgcn_mfma_f32_16x16x32_bf16(af[2][0], bfr[t][2], a0, 0, 0, 0);
        a1 = __builtin_amdgcn_mfma_f32_16x16x32_bf16(af[2][1], bfr[t][2], a1, 0, 0, 0);
        const bool ok = (unsigned)(gb - 4 + o) < (unsigned)LLEN;
        #pragma unroll
        for (int r = 0; r < 4; ++r) {
            a0[r] = ok ? fmaxf(a0[r], 0.f) : 0.f;
            a1[r] = ok ? fmaxf(a1[r], 0.f) : 0.f;
        }
        if (!LAST) {
            bf16x4 p0, p1;
            #pragma unroll
            for (int r = 0; r < 4; ++r) { p0[r] = (__bf16)a0[r]; p1[r] = (__bf16)a1[r]; }
            *reinterpret_cast<bf16x4*>(&bout[o * RSTR + co0]) = p0;
            *reinterpret_cast<bf16x4*>(&bout[o * RSTR + 16 + co0]) = p1;
        } else {
            #pragma unroll
            for (int r = 0; r < 4; ++r) { vs[r] += a0[r]; vs[4 + r] += a1[r]; }
        }
    }
}

__global__ __launch_bounds__(256, 4) void conv_kernel(
        const float* __restrict__ cin,   // [B][16][L]
        const float* __restrict__ xin,   // [B][8][L]
        const unsigned short* __restrict__ wf,  // this t: [4][3][2][64][8]
        const float* __restrict__ b0p,   // [32]   (this t)
        const float* __restrict__ bhp,   // [3][32](this t)
        float* __restrict__ hbar) {      // [B][32] sums (atomic)
    __shared__ __align__(16) __bf16 lds[4][2][LWORDS];
    __shared__ float psum[4][HID];

    const int tid = threadIdx.x;
    const int lane = tid & 63, wv = tid >> 6;
    const int b = blockIdx.y;
    const int gb = blockIdx.x * (4 * WPW) + wv * WPW;
    const int prow = lane & 15, grp = lane >> 4;

    __bf16* bufA = &lds[wv][0][0];
    __bf16* bufB = &lds[wv][1][0];

    // ---- stage: lane p = row p. 24 coalesced scalar loads ARE the transpose.
    {
        const int p = lane;
        int g = gb - 4 + p;
        int gc = min(max(g, 0), LLEN - 1);
        bool ok = (g == gc);
        const float* cbp = cin + (size_t)b * CCOND * LLEN + gc;
        const float* xbp = xin + (size_t)b * CX * LLEN + gc;
        float v[CIN0];
        #pragma unroll
        for (int ch = 0; ch < CCOND; ++ch) v[ch] = cbp[(size_t)ch * LLEN];
        #pragma unroll
        for (int ch = 0; ch < CX; ++ch) v[CCOND + ch] = xbp[(size_t)ch * LLEN];
        #pragma unroll
        for (int ch = 0; ch < CIN0; ++ch) v[ch] = ok ? v[ch] : 0.f;
        bf16x8 pk0, pk1, pk2;
        #pragma unroll
        for (int j = 0; j < 8; ++j) {
            pk0[j] = (__bf16)v[j];
            pk1[j] = (__bf16)v[8 + j];
            pk2[j] = (__bf16)v[16 + j];
        }
        if (p < SROWS) {
            *reinterpret_cast<bf16x8*>(&bufA[p * RSTR])      = pk0;
            *reinterpret_cast<bf16x8*>(&bufA[p * RSTR + 8])  = pk1;
            *reinterpret_cast<bf16x8*>(&bufA[p * RSTR + 16]) = pk2;
            *reinterpret_cast<uint4*>(&bufA[p * RSTR + 24])  = make_uint4(0, 0, 0, 0);
        }
    }
    WAVE_SYNC();

    float vs[8] = {0.f, 0.f, 0.f, 0.f, 0.f, 0.f, 0.f, 0.f};
    const int s0[4] = {1, 17, 33, 39};
    const int s1[4] = {2, 18, 34, 38};
    const int s2[4] = {3, 19, 35, 37};
    const int s3[3] = {4, 20, 36};
    wconv_layer<4, 0>(bufA, bufB, wf,        b0p,      s0, gb, lane, vs);
    WAVE_SYNC();
    wconv_layer<4, 0>(bufB, bufA, wf + 3072, bhp,      s1, gb, lane, vs);
    WAVE_SYNC();
    wconv_layer<4, 0>(bufA, bufB, wf + 6144, bhp + 32, s2, gb, lane, vs);
    WAVE_SYNC();
    wconv_layer<3, 1>(bufB, bufA, wf + 9216, bhp + 64, s3, gb, lane, vs);

    // reduce vs over the 16 position-lanes via DPP row rotations (VALU pipe)
    #pragma unroll
    for (int r = 0; r < 8; ++r) {
        vs[r] += dpp_movf<RROR8>(vs[r]);
        vs[r] += dpp_movf<RROR4>(vs[r]);
        vs[r] += dpp_movf<RROR2>(vs[r]);
        vs[r] += dpp_movf<RROR1>(vs[r]);
    }
    const int co0 = grp * 4;
    if (prow == 0) {
        #pragma unroll
        for (int r = 0; r < 4; ++r) {
            psum[wv][co0 + r] = vs[r];
            psum[wv][16 + co0 + r] = vs[4 + r];
        }
    }
    __syncthreads();
    if (tid < HID) {
        float s = psum[0][tid] + psum[1][tid] + psum[2][tid] + psum[3][tid];
        atomicAdd(&hbar[b * HID + tid], s);
    }
}

// ---------------------------------------------------------------- spline prep
__device__ __forceinline__ float softplusf(float v) {
    return fmaxf(v, 0.f) + log1pf(expf(-fabsf(v)));
}

// One thread per (b,c): p = w_out * mean(h) + b_out, then knot arrays.
// w_out and this block's hbar slice staged in LDS (padded, conflict-free).
// Record layout (stride PSTR): cw[0..8], ch[9..17], w[18..25], h[26..33], d[34..42]
__global__ __launch_bounds__(256) void params_kernel(
        const float* __restrict__ hbar,   // [B][32] sums
        const float* __restrict__ w_out,  // [184][32] for this t
        const float* __restrict__ b_out,  // [184]
        float* __restrict__ params) {
    __shared__ float wsh[POUT][HID + 1];
    __shared__ float hsh[32][HID];
    const int tid = threadIdx.x;
    const float invL = 1.0f / (float)LLEN;
    for (int i = tid; i < POUT * HID; i += 256)
        wsh[i >> 5][i & 31] = w_out[i];
    for (int i = tid; i < 32 * HID; i += 256)
        hsh[i >> 5][i & 31] = hbar[blockIdx.x * 32 * HID + i] * invL;
    __syncthreads();

    int tg = blockIdx.x * 256 + tid;
    int bl = tid >> 3, c = tid & 7;

    float p[PDIM];
    #pragma unroll
    for (int j = 0; j < PDIM; j++) {
        int cp = c * PDIM + j;
        float acc = b_out[cp];
        #pragma unroll
        for (int h = 0; h < HID; h++) acc = fmaf(wsh[cp][h], hsh[bl][h], acc);
        p[j] = acc;
    }

    float* out = params + (size_t)tg * PSTR;

    // widths -> knot x positions
    {
        float mx = p[0];
        #pragma unroll
        for (int k = 1; k < 8; k++) mx = fmaxf(mx, p[k]);
        float e[8], se = 0.f;
        #pragma unroll
        for (int k = 0; k < 8; k++) { e[k] = expf(p[k] - mx); se += e[k]; }
        float inv = 1.f / se, cum = 0.f;
        float cw[9]; cw[0] = -3.f;
        #pragma unroll
        for (int k = 0; k < 8; k++) {
            float wk = 1e-3f + (1.f - 8e-3f) * (e[k] * inv);
            cum += wk;
            cw[k + 1] = 6.f * cum - 3.f;
        }
        #pragma unroll
        for (int k = 0; k < 9; k++) out[k] = cw[k];
        #pragma unroll
        for (int k = 0; k < 8; k++) out[18 + k] = cw[k + 1] - cw[k];
    }
    // heights -> knot y positions
    {
        float mx = p[8];
        #pragma unroll
        for (int k = 1; k < 8; k++) mx = fmaxf(mx, p[8 + k]);
        float e[8], se = 0.f;
        #pragma unroll
        for (int k = 0; k < 8; k++) { e[k] = expf(p[8 + k] - mx); se += e[k]; }
        float inv = 1.f / se, cum = 0.f;
        float ch[9]; ch[0] = -3.f;
        #pragma unroll
        for (int k = 0; k < 8; k++) {
            float hk = 1e-3f + (1.f - 8e-3f) * (e[k] * inv);
            cum += hk;
            ch[k + 1] = 6.f * cum - 3.f;
        }
        #pragma unroll
        for (int k = 0; k < 9; k++) out[9 + k] = ch[k];
        #pragma unroll
        for (int k = 0; k < 8; k++) out[26 + k] = ch[k + 1] - ch[k];
    }
    // derivatives (boundary = 1)
    out[34] = 1.f;
    #pragma unroll
    for (int k = 0; k < 7; k++) out[35 + k] = 1e-3f + softplusf(p[16 + k]);
    out[42] = 1.f;
}

// ---------------------------------------------------------------- RQS inverse
// 8 elements/thread (2x float4, hoisted loads). Params wave-uniform -> SGPRs;
// bin gather = branchless cndmask tree; raw v_log/v_sqrt/v_rcp.
__device__ __forceinline__ void rqs_elem(
        const float* cw, const float* chv, const float* wd,
        const float* hg, const float* dv,
        float y, float& ov, float& ldsum) {
    bool inside = fabsf(y) <= 3.0f;
    float yc = fminf(fmaxf(y, -3.f), 3.f);

    float icw = cw[0], iw = wd[0], ich = chv[0], ih = hg[0];
    float dk = dv[0], dk1 = dv[1];
    #pragma unroll
    for (int k = 1; k < 8; k++) {
        bool c = yc >= chv[k];
        icw = c ? cw[k]  : icw;
        iw  = c ? wd[k]  : iw;
        ich = c ? chv[k] : ich;
        ih  = c ? hg[k]  : ih;
        dk  = c ? dv[k]  : dk;
        dk1 = c ? dv[k + 1] : dk1;
    }
    float s  = ih * __builtin_amdgcn_rcpf(iw);
    float dy = yc - ich;
    float t1 = dk + dk1 - 2.f * s;
    float a  = ih * (s - dk) + dy * t1;
    float bq = ih * dk - dy * t1;
    float cq = -s * dy;
    float disc = fmaxf(bq * bq - 4.f * a * cq, 0.f);
    float den  = -bq - __builtin_amdgcn_sqrtf(disc);
    float root = (2.f * cq) * __builtin_amdgcn_rcpf(den);
    float om = 1.f - root;
    float outv  = fmaf(root, iw, icw);
    float denom = fmaf(t1 * root, om, s);
    float dnum  = s * s * (dk1 * root * root + 2.f * s * root * om + dk * om * om);
    float ld = (2.f * __builtin_amdgcn_logf(denom) - __builtin_amdgcn_logf(dnum))
               * 0.69314718055994531f;
    ov = inside ? outv : y;
    ldsum += inside ? ld : 0.f;
}

__global__ __launch_bounds__(256) void rqs_kernel(const float* __restrict__ params,
                                                  const float* __restrict__ xin,
                                                  float* __restrict__ xout,
                                                  float* __restrict__ logdet) {
    const int bc = blockIdx.y;
    const float* __restrict__ pp = params + (size_t)bc * PSTR;
    float cw[9], chv[9], wd[8], hg[8], dv[9];
    #pragma unroll
    for (int k = 0; k < 9; k++) cw[k] = pp[k];
    #pragma unroll
    for (int k = 0; k < 9; k++) chv[k] = pp[9 + k];
    #pragma unroll
    for (int k = 0; k < 8; k++) wd[k] = pp[18 + k];
    #pragma unroll
    for (int k = 0; k < 8; k++) hg[k] = pp[26 + k];
    #pragma unroll
    for (int k = 0; k < 9; k++) dv[k] = pp[34 + k];

    const int tid = threadIdx.x;
    size_t base0 = (size_t)bc * LLEN + (size_t)blockIdx.x * 2048 + (size_t)tid * 4;
    size_t base1 = base0 + 1024;
    float4 ya = *reinterpret_cast<const float4*>(xin + base0);
    float4 yb = *reinterpret_cast<const float4*>(xin + base1);

    float ldsum = 0.f;
    float4 oa, ob;
    rqs_elem(cw, chv, wd, hg, dv, ya.x, oa.x, ldsum);
    rqs_elem(cw, chv, wd, hg, dv, ya.y, oa.y, ldsum);
    rqs_elem(cw, chv, wd, hg, dv, ya.z, oa.z, ldsum);
    rqs_elem(cw, chv, wd, hg, dv, ya.w, oa.w, ldsum);
    rqs_elem(cw, chv, wd, hg, dv, yb.x, ob.x, ldsum);
    rqs_elem(cw, chv, wd, hg, dv, yb.y, ob.y, ldsum);
    rqs_elem(cw, chv, wd, hg, dv, yb.z, ob.z, ldsum);
    rqs_elem(cw, chv, wd, hg, dv, yb.w, ob.w, ldsum);
    *reinterpret_cast<float4*>(xout + base0) = oa;
    *reinterpret_cast<float4*>(xout + base1) = ob;

    #pragma unroll
    for (int off = 32; off > 0; off >>= 1) ldsum += __shfl_xor(ldsum, off, 64);
    __shared__ float red[4];
    if ((tid & 63) == 0) red[tid >> 6] = ldsum;
    __syncthreads();
    if (tid == 0) {
        float sb = red[0] + red[1] + red[2] + red[3];
        atomicAdd(&logdet[bc >> 3], sb * (1.0f / (float)LLEN));
    }
}

// ---------------------------------------------------------------- launch
extern "C" void kernel_launch(void* const* d_in, const int* in_sizes, int n_in,
                              void* d_out, int out_size, void* d_ws, size_t ws_size,
                              hipStream_t stream) {
    const float* cin   = (const float*)d_in[1];
    const float* noise = (const float*)d_in[2];
    const float* w0    = (const float*)d_in[3];
    const float* b0    = (const float*)d_in[4];
    const float* wh    = (const float*)d_in[5];
    const float* bh    = (const float*)d_in[6];
    const float* w_out = (const float*)d_in[7];
    const float* b_out = (const float*)d_in[8];

    float* xout   = (float*)d_out;                       // [128*8*8192]
    float* logdet = xout + (size_t)BATCH * CX * LLEN;    // [128]

    float* ws     = (float*)d_ws;
    float* hbar0  = ws;                                  // 4096 floats
    float* hbar1  = ws + 4096;                           // 4096 floats
    float* params = ws + 8192;                           // 1024*48 floats
    unsigned short* wf = (unsigned short*)(ws + 8192 + 1024 * PSTR);  // 24576 ushorts

    zero_kernel<<<32, 256, 0, stream>>>(ws, logdet);     // hbar0|hbar1 + logdet
    repack_frag_kernel<<<96, 256, 0, stream>>>(w0, wh, wf);

    for (int t = 0; t < NSTEP; t++) {
        const float* xcur = (t == 0) ? noise : xout;
        float* hbar = (t == 0) ? hbar0 : hbar1;
        conv_kernel<<<dim3(GRIDX, BATCH), 256, 0, stream>>>(
            cin, xcur,
            wf + t * 12288, b0 + t * HID, bh + t * 3 * HID,
            hbar);
        params_kernel<<<BATCH * CX / 256, 256, 0, stream>>>(
            hbar, w_out + t * POUT * HID, b_out + t * POUT, params);
        rqs_kernel<<<dim3(LLEN / 2048, BATCH * CX), 256, 0, stream>>>(
            params, xcur, xout, logdet);
    }
}

// Round 9
// 163.754 us; speedup vs baseline: 8.8024x; 1.1404x over previous
//
#include <hip/hip_runtime.h>
#include <hip/hip_bf16.h>

// Sizes (fixed by the problem)
#define BATCH 128
#define CCOND 16          // conditioning channels
#define CX    8           // flow channels
#define CIN0  24          // CCOND + CX
#define HID   32
#define LLEN  8192
#define NSTEP 2
#define PDIM  23          // 3K-1, K=8
#define POUT  184         // PDIM * CX
#define PSTR  48          // per-(b,c) param record stride in ws

// conv tiling: one wave = one independent 48-output window, no block barriers
#define WPW   48          // final outputs per wave
#define SROWS 56          // staged rows per wave: g in [gb-4, gb+52)
#define RSTR  40          // bf16 stride per row (80 B, 16B-aligned, 2-way banks)
#define LWORDS (SROWS * RSTR)   // 2240 bf16 per buffer
#define GRIDX 43          // ceil(8192 / 192)

typedef __bf16 bf16x8 __attribute__((ext_vector_type(8)));
typedef __bf16 bf16x4 __attribute__((ext_vector_type(4)));
typedef float  f32x4  __attribute__((ext_vector_type(4)));

// wave-local LDS ordering fence (DS pipe is in-order per wave)
#define WAVE_SYNC() asm volatile("s_waitcnt lgkmcnt(0)" ::: "memory")

// DPP lane-move (VALU pipe) for the 16-lane reduce
template<int CTRL>
__device__ __forceinline__ float dpp_movf(float v) {
    return __int_as_float(
        __builtin_amdgcn_mov_dpp(__float_as_int(v), CTRL, 0xF, 0xF, true));
}
#define RROR1 0x121
#define RROR2 0x122
#define RROR4 0x124
#define RROR8 0x128

__device__ __forceinline__ unsigned short f2bf(float f) {
    unsigned u = __float_as_uint(f);
    return (unsigned short)((u + 0x7FFFu + ((u >> 16) & 1u)) >> 16);
}

// ---------------------------------------------------------------- util
// zeros hbar0|hbar1 (ws[0..8192)) and logdet[0..128)
__global__ void zero_kernel(float* __restrict__ ws, float* __restrict__ logdet) {
    int i = blockIdx.x * 256 + threadIdx.x;
    ws[i] = 0.f;
    if (i < BATCH) logdet[i] = 0.f;
}

// Pack conv weights into exact per-lane MFMA A-fragment order (bf16).
// wf[t][layer][s][mt][lane][j]; element = W[co = mt*16+(lane&15)]
//                                          [ci = (lane>>4)*8+j][koff = s]
__global__ void repack_frag_kernel(const float* __restrict__ w0,   // [2][32][24][3]
                                   const float* __restrict__ wh,   // [2][3][32][32][3]
                                   unsigned short* __restrict__ wf) {
    int i = blockIdx.x * 256 + threadIdx.x;     // 24576 total
    int j = i & 7, lane = (i >> 3) & 63, q = i >> 9;
    int mt = q & 1; q >>= 1;
    int s = q % 3;  q /= 3;
    int l = q & 3, t = q >> 2;
    int m = mt * 16 + (lane & 15);
    int ci = (lane >> 4) * 8 + j;
    float v;
    if (l == 0)
        v = (ci < CIN0) ? w0[((t * HID + m) * CIN0 + ci) * 3 + s] : 0.f;
    else
        v = wh[(((t * 3 + (l - 1)) * HID + m) * HID + ci) * 3 + s];
    wf[i] = f2bf(v);
}

// ---------------------------------------------------------------- fused convs
// One layer over the wave's private window: bin rows [o-1,o+1] -> bout row o,
// o = starts[t] + prow (overlapping tiles recompute rows idempotently).
// EDGE: rows whose global g is outside [0,L) forced to 0 (SAME zero padding);
// interior waves (97%) skip all masking ops.
template<int NTL, int LAST, bool EDGE>
__device__ __forceinline__ void wconv_layer(
        const __bf16* __restrict__ bin, __bf16* __restrict__ bout,
        const unsigned short* __restrict__ wl, const float* __restrict__ bp,
        const int (&starts)[NTL], int gb, int lane, float* __restrict__ vs) {
    const int prow = lane & 15, grp = lane >> 4;
    const int ci0 = grp * 8, co0 = grp * 4;

    bf16x8 af[3][2];
    #pragma unroll
    for (int s = 0; s < 3; ++s)
        #pragma unroll
        for (int mt = 0; mt < 2; ++mt)
            af[s][mt] = *reinterpret_cast<const bf16x8*>(
                wl + ((s * 2 + mt) << 9) + (lane << 3));
    f32x4 bias0 = *reinterpret_cast<const f32x4*>(bp + co0);
    f32x4 bias1 = *reinterpret_cast<const f32x4*>(bp + 16 + co0);

    // issue ALL fragment reads first; barrier pins them ahead of the MFMAs
    bf16x8 bfr[NTL][3];
    #pragma unroll
    for (int t = 0; t < NTL; ++t) {
        const int o = starts[t] + prow;
        #pragma unroll
        for (int tap = 0; tap < 3; ++tap)
            bfr[t][tap] = *reinterpret_cast<const bf16x8*>(
                &bin[(o + tap - 1) * RSTR + ci0]);
    }
    __builtin_amdgcn_sched_barrier(0);

    #pragma unroll
    for (int t = 0; t < NTL; ++t) {
        const int o = starts[t] + prow;
        f32x4 a0 = bias0, a1 = bias1;
        a0 = __builtin_amdgcn_mfma_f32_16x16x32_bf16(af[0][0], bfr[t][0], a0, 0, 0, 0);
        a1 = __builtin_amdgcn_mfma_f32_16x16x32_bf16(af[0][1], bfr[t][0], a1, 0, 0, 0);
        a0 = __builtin_amdgcn_mfma_f32_16x16x32_bf16(af[1][0], bfr[t][1], a0, 0, 0, 0);
        a1 = __builtin_amdgcn_mfma_f32_16x16x32_bf16(af[1][1], bfr[t][1], a1, 0, 0, 0);
        a0 = __builtin_amdgcn_mfma_f32_16x16x32_bf16(af[2][0], bfr[t][2], a0, 0, 0, 0);
        a1 = __builtin_amdgcn_mfma_f32_16x16x32_bf16(af[2][1], bfr[t][2], a1, 0, 0, 0);
        bool ok = true;
        if (EDGE) ok = (unsigned)(gb - 4 + o) < (unsigned)LLEN;
        #pragma unroll
        for (int r = 0; r < 4; ++r) {
            a0[r] = fmaxf(a0[r], 0.f);
            a1[r] = fmaxf(a1[r], 0.f);
            if (EDGE) { a0[r] = ok ? a0[r] : 0.f; a1[r] = ok ? a1[r] : 0.f; }
        }
        if (!LAST) {
            bf16x4 p0, p1;
            #pragma unroll
            for (int r = 0; r < 4; ++r) { p0[r] = (__bf16)a0[r]; p1[r] = (__bf16)a1[r]; }
            *reinterpret_cast<bf16x4*>(&bout[o * RSTR + co0]) = p0;
            *reinterpret_cast<bf16x4*>(&bout[o * RSTR + 16 + co0]) = p1;
        } else {
            #pragma unroll
            for (int r = 0; r < 4; ++r) { vs[r] += a0[r]; vs[4 + r] += a1[r]; }
        }
    }
}

template<bool EDGE>
__device__ __forceinline__ void conv_body(
        const float* __restrict__ cin, const float* __restrict__ xin,
        const unsigned short* __restrict__ wf,
        const float* __restrict__ b0p, const float* __restrict__ bhp,
        __bf16* __restrict__ bufA, __bf16* __restrict__ bufB,
        int b, int gb, int lane, float* __restrict__ vs) {
    // ---- stage: lane p = row p. 24 coalesced scalar loads ARE the transpose.
    if (lane < SROWS) {
        const int p = lane;
        int g = gb - 4 + p;
        int gc = g;
        bool ok = true;
        if (EDGE) { gc = min(max(g, 0), LLEN - 1); ok = (g == gc); }
        const float* cbp = cin + (size_t)b * CCOND * LLEN + gc;
        const float* xbp = xin + (size_t)b * CX * LLEN + gc;
        float v[CIN0];
        #pragma unroll
        for (int ch = 0; ch < CCOND; ++ch) v[ch] = cbp[(size_t)ch * LLEN];
        #pragma unroll
        for (int ch = 0; ch < CX; ++ch) v[CCOND + ch] = xbp[(size_t)ch * LLEN];
        if (EDGE) {
            #pragma unroll
            for (int ch = 0; ch < CIN0; ++ch) v[ch] = ok ? v[ch] : 0.f;
        }
        bf16x8 pk0, pk1, pk2;
        #pragma unroll
        for (int j = 0; j < 8; ++j) {
            pk0[j] = (__bf16)v[j];
            pk1[j] = (__bf16)v[8 + j];
            pk2[j] = (__bf16)v[16 + j];
        }
        *reinterpret_cast<bf16x8*>(&bufA[p * RSTR])      = pk0;
        *reinterpret_cast<bf16x8*>(&bufA[p * RSTR + 8])  = pk1;
        *reinterpret_cast<bf16x8*>(&bufA[p * RSTR + 16]) = pk2;
        *reinterpret_cast<uint4*>(&bufA[p * RSTR + 24])  = make_uint4(0, 0, 0, 0);
    }
    WAVE_SYNC();

    const int s0[4] = {1, 17, 33, 39};
    const int s1[4] = {2, 18, 34, 38};
    const int s2[4] = {3, 19, 35, 37};
    const int s3[3] = {4, 20, 36};
    wconv_layer<4, 0, EDGE>(bufA, bufB, wf,        b0p,      s0, gb, lane, vs);
    WAVE_SYNC();
    wconv_layer<4, 0, EDGE>(bufB, bufA, wf + 3072, bhp,      s1, gb, lane, vs);
    WAVE_SYNC();
    wconv_layer<4, 0, EDGE>(bufA, bufB, wf + 6144, bhp + 32, s2, gb, lane, vs);
    WAVE_SYNC();
    wconv_layer<3, 1, EDGE>(bufB, bufA, wf + 9216, bhp + 64, s3, gb, lane, vs);
}

__global__ __launch_bounds__(256, 4) void conv_kernel(
        const float* __restrict__ cin,   // [B][16][L]
        const float* __restrict__ xin,   // [B][8][L]
        const unsigned short* __restrict__ wf,  // this t: [4][3][2][64][8]
        const float* __restrict__ b0p,   // [32]   (this t)
        const float* __restrict__ bhp,   // [3][32](this t)
        float* __restrict__ hbar) {      // [B][32] sums (atomic)
    __shared__ __align__(16) __bf16 lds[4][2][LWORDS];
    __shared__ float psum[4][HID];

    const int tid = threadIdx.x;
    const int lane = tid & 63, wv = tid >> 6;
    const int b = blockIdx.y;
    const int gb = blockIdx.x * (4 * WPW) + wv * WPW;
    const int prow = lane & 15, grp = lane >> 4;

    __bf16* bufA = &lds[wv][0][0];
    __bf16* bufB = &lds[wv][1][0];

    float vs[8] = {0.f, 0.f, 0.f, 0.f, 0.f, 0.f, 0.f, 0.f};
    const bool edge = (gb < 4) || (gb + SROWS - 4 > LLEN);
    if (edge)
        conv_body<true >(cin, xin, wf, b0p, bhp, bufA, bufB, b, gb, lane, vs);
    else
        conv_body<false>(cin, xin, wf, b0p, bhp, bufA, bufB, b, gb, lane, vs);

    // reduce vs over the 16 position-lanes via DPP row rotations (VALU pipe)
    #pragma unroll
    for (int r = 0; r < 8; ++r) {
        vs[r] += dpp_movf<RROR8>(vs[r]);
        vs[r] += dpp_movf<RROR4>(vs[r]);
        vs[r] += dpp_movf<RROR2>(vs[r]);
        vs[r] += dpp_movf<RROR1>(vs[r]);
    }
    const int co0 = grp * 4;
    if (prow == 0) {
        #pragma unroll
        for (int r = 0; r < 4; ++r) {
            psum[wv][co0 + r] = vs[r];
            psum[wv][16 + co0 + r] = vs[4 + r];
        }
    }
    __syncthreads();
    if (tid < HID) {
        float s = psum[0][tid] + psum[1][tid] + psum[2][tid] + psum[3][tid];
        atomicAdd(&hbar[b * HID + tid], s);
    }
}

// ---------------------------------------------------------------- spline prep
__device__ __forceinline__ float softplusf(float v) {
    return fmaxf(v, 0.f) + log1pf(expf(-fabsf(v)));
}

// One thread per (b,c): p = w_out * mean(h) + b_out, then knot arrays.
// w_out and this block's hbar slice staged in LDS (padded, conflict-free).
// Record layout (stride PSTR): cw[0..8], ch[9..17], w[18..25], h[26..33], d[34..42]
__global__ __launch_bounds__(256) void params_kernel(
        const float* __restrict__ hbar,   // [B][32] sums
        const float* __restrict__ w_out,  // [184][32] for this t
        const float* __restrict__ b_out,  // [184]
        float* __restrict__ params) {
    __shared__ float wsh[POUT][HID + 1];
    __shared__ float hsh[32][HID];
    const int tid = threadIdx.x;
    const float invL = 1.0f / (float)LLEN;
    for (int i = tid; i < POUT * HID; i += 256)
        wsh[i >> 5][i & 31] = w_out[i];
    for (int i = tid; i < 32 * HID; i += 256)
        hsh[i >> 5][i & 31] = hbar[blockIdx.x * 32 * HID + i] * invL;
    __syncthreads();

    int tg = blockIdx.x * 256 + tid;
    int bl = tid >> 3, c = tid & 7;

    float p[PDIM];
    #pragma unroll
    for (int j = 0; j < PDIM; j++) {
        int cp = c * PDIM + j;
        float acc = b_out[cp];
        #pragma unroll
        for (int h = 0; h < HID; h++) acc = fmaf(wsh[cp][h], hsh[bl][h], acc);
        p[j] = acc;
    }

    float* out = params + (size_t)tg * PSTR;

    // widths -> knot x positions
    {
        float mx = p[0];
        #pragma unroll
        for (int k = 1; k < 8; k++) mx = fmaxf(mx, p[k]);
        float e[8], se = 0.f;
        #pragma unroll
        for (int k = 0; k < 8; k++) { e[k] = expf(p[k] - mx); se += e[k]; }
        float inv = 1.f / se, cum = 0.f;
        float cw[9]; cw[0] = -3.f;
        #pragma unroll
        for (int k = 0; k < 8; k++) {
            float wk = 1e-3f + (1.f - 8e-3f) * (e[k] * inv);
            cum += wk;
            cw[k + 1] = 6.f * cum - 3.f;
        }
        #pragma unroll
        for (int k = 0; k < 9; k++) out[k] = cw[k];
        #pragma unroll
        for (int k = 0; k < 8; k++) out[18 + k] = cw[k + 1] - cw[k];
    }
    // heights -> knot y positions
    {
        float mx = p[8];
        #pragma unroll
        for (int k = 1; k < 8; k++) mx = fmaxf(mx, p[8 + k]);
        float e[8], se = 0.f;
        #pragma unroll
        for (int k = 0; k < 8; k++) { e[k] = expf(p[8 + k] - mx); se += e[k]; }
        float inv = 1.f / se, cum = 0.f;
        float ch[9]; ch[0] = -3.f;
        #pragma unroll
        for (int k = 0; k < 8; k++) {
            float hk = 1e-3f + (1.f - 8e-3f) * (e[k] * inv);
            cum += hk;
            ch[k + 1] = 6.f * cum - 3.f;
        }
        #pragma unroll
        for (int k = 0; k < 9; k++) out[9 + k] = ch[k];
        #pragma unroll
        for (int k = 0; k < 8; k++) out[26 + k] = ch[k + 1] - ch[k];
    }
    // derivatives (boundary = 1)
    out[34] = 1.f;
    #pragma unroll
    for (int k = 0; k < 7; k++) out[35 + k] = 1e-3f + softplusf(p[16 + k]);
    out[42] = 1.f;
}

// ---------------------------------------------------------------- RQS inverse
// 16 elements/thread (4x float4, hoisted loads). Params wave-uniform -> SGPRs;
// bin gather = branchless cndmask tree; raw v_log/v_sqrt/v_rcp.
__device__ __forceinline__ void rqs_elem(
        const float* cw, const float* chv, const float* wd,
        const float* hg, const float* dv,
        float y, float& ov, float& ldsum) {
    bool inside = fabsf(y) <= 3.0f;
    float yc = fminf(fmaxf(y, -3.f), 3.f);

    float icw = cw[0], iw = wd[0], ich = chv[0], ih = hg[0];
    float dk = dv[0], dk1 = dv[1];
    #pragma unroll
    for (int k = 1; k < 8; k++) {
        bool c = yc >= chv[k];
        icw = c ? cw[k]  : icw;
        iw  = c ? wd[k]  : iw;
        ich = c ? chv[k] : ich;
        ih  = c ? hg[k]  : ih;
        dk  = c ? dv[k]  : dk;
        dk1 = c ? dv[k + 1] : dk1;
    }
    float s  = ih * __builtin_amdgcn_rcpf(iw);
    float dy = yc - ich;
    float t1 = dk + dk1 - 2.f * s;
    float a  = ih * (s - dk) + dy * t1;
    float bq = ih * dk - dy * t1;
    float cq = -s * dy;
    float disc = fmaxf(bq * bq - 4.f * a * cq, 0.f);
    float den  = -bq - __builtin_amdgcn_sqrtf(disc);
    float root = (2.f * cq) * __builtin_amdgcn_rcpf(den);
    float om = 1.f - root;
    float outv  = fmaf(root, iw, icw);
    float denom = fmaf(t1 * root, om, s);
    float dnum  = s * s * (dk1 * root * root + 2.f * s * root * om + dk * om * om);
    float ld = (2.f * __builtin_amdgcn_logf(denom) - __builtin_amdgcn_logf(dnum))
               * 0.69314718055994531f;
    ov = inside ? outv : y;
    ldsum += inside ? ld : 0.f;
}

__global__ __launch_bounds__(256) void rqs_kernel(const float* __restrict__ params,
                                                  const float* __restrict__ xin,
                                                  float* __restrict__ xout,
                                                  float* __restrict__ logdet) {
    const int bc = blockIdx.y;
    const float* __restrict__ pp = params + (size_t)bc * PSTR;
    float cw[9], chv[9], wd[8], hg[8], dv[9];
    #pragma unroll
    for (int k = 0; k < 9; k++) cw[k] = pp[k];
    #pragma unroll
    for (int k = 0; k < 9; k++) chv[k] = pp[9 + k];
    #pragma unroll
    for (int k = 0; k < 8; k++) wd[k] = pp[18 + k];
    #pragma unroll
    for (int k = 0; k < 8; k++) hg[k] = pp[26 + k];
    #pragma unroll
    for (int k = 0; k < 9; k++) dv[k] = pp[34 + k];

    const int tid = threadIdx.x;
    size_t base = (size_t)bc * LLEN + (size_t)blockIdx.x * 4096 + (size_t)tid * 4;
    float4 y4[4];
    #pragma unroll
    for (int q = 0; q < 4; ++q)
        y4[q] = *reinterpret_cast<const float4*>(xin + base + q * 1024);

    float ldsum = 0.f;
    float4 o4[4];
    #pragma unroll
    for (int q = 0; q < 4; ++q) {
        rqs_elem(cw, chv, wd, hg, dv, y4[q].x, o4[q].x, ldsum);
        rqs_elem(cw, chv, wd, hg, dv, y4[q].y, o4[q].y, ldsum);
        rqs_elem(cw, chv, wd, hg, dv, y4[q].z, o4[q].z, ldsum);
        rqs_elem(cw, chv, wd, hg, dv, y4[q].w, o4[q].w, ldsum);
    }
    #pragma unroll
    for (int q = 0; q < 4; ++q)
        *reinterpret_cast<float4*>(xout + base + q * 1024) = o4[q];

    #pragma unroll
    for (int off = 32; off > 0; off >>= 1) ldsum += __shfl_xor(ldsum, off, 64);
    __shared__ float red[4];
    if ((tid & 63) == 0) red[tid >> 6] = ldsum;
    __syncthreads();
    if (tid == 0) {
        float sb = red[0] + red[1] + red[2] + red[3];
        atomicAdd(&logdet[bc >> 3], sb * (1.0f / (float)LLEN));
    }
}

// ---------------------------------------------------------------- launch
extern "C" void kernel_launch(void* const* d_in, const int* in_sizes, int n_in,
                              void* d_out, int out_size, void* d_ws, size_t ws_size,
                              hipStream_t stream) {
    const float* cin   = (const float*)d_in[1];
    const float* noise = (const float*)d_in[2];
    const float* w0    = (const float*)d_in[3];
    const float* b0    = (const float*)d_in[4];
    const float* wh    = (const float*)d_in[5];
    const float* bh    = (const float*)d_in[6];
    const float* w_out = (const float*)d_in[7];
    const float* b_out = (const float*)d_in[8];

    float* xout   = (float*)d_out;                       // [128*8*8192]
    float* logdet = xout + (size_t)BATCH * CX * LLEN;    // [128]

    float* ws     = (float*)d_ws;
    float* hbar0  = ws;                                  // 4096 floats
    float* hbar1  = ws + 4096;                           // 4096 floats
    float* params = ws + 8192;                           // 1024*48 floats
    unsigned short* wf = (unsigned short*)(ws + 8192 + 1024 * PSTR);  // 24576 ushorts

    zero_kernel<<<32, 256, 0, stream>>>(ws, logdet);     // hbar0|hbar1 + logdet
    repack_frag_kernel<<<96, 256, 0, stream>>>(w0, wh, wf);

    for (int t = 0; t < NSTEP; t++) {
        const float* xcur = (t == 0) ? noise : xout;
        float* hbar = (t == 0) ? hbar0 : hbar1;
        conv_kernel<<<dim3(GRIDX, BATCH), 256, 0, stream>>>(
            cin, xcur,
            wf + t * 12288, b0 + t * HID, bh + t * 3 * HID,
            hbar);
        params_kernel<<<BATCH * CX / 256, 256, 0, stream>>>(
            hbar, w_out + t * POUT * HID, b_out + t * POUT, params);
        rqs_kernel<<<dim3(LLEN / 4096, BATCH * CX), 256, 0, stream>>>(
            params, xcur, xout, logdet);
    }
}